// Round 1
// baseline (1360.355 us; speedup 1.0000x reference)
//
#include <hip/hip_runtime.h>
#include <stdint.h>

#define T_TOKENS 16384
#define HID 1024
#define INTERM 2048
#define NEXP 8

typedef __bf16 bf16x8 __attribute__((ext_vector_type(8)));
typedef float f32x4 __attribute__((ext_vector_type(4)));

// ---------- helpers ----------
__device__ __forceinline__ unsigned short f2bf(float f) {
  union { float f; uint32_t u; } v; v.f = f;
  uint32_t u = v.u + 0x7fffu + ((v.u >> 16) & 1u);
  return (unsigned short)(u >> 16);
}

__device__ __forceinline__ void async16(const void* g, void* l) {
  // CK idiom: generic->AS1/AS3 via uintptr_t (LDS generic addr low 32 bits == ds offset)
  auto gp = (const __attribute__((address_space(1))) uint32_t*)(uintptr_t)g;
  auto lp = (__attribute__((address_space(3))) uint32_t*)(uintptr_t)l;
  __builtin_amdgcn_global_load_lds(gp, lp, 16, 0, 0);
}

// ---------- fp32 -> bf16 cast ----------
__global__ void cast_bf16_kernel(const float* __restrict__ in,
                                 unsigned short* __restrict__ out, int n) {
  int stride = gridDim.x * blockDim.x;
  for (int i = blockIdx.x * blockDim.x + threadIdx.x; i < (n >> 2); i += stride) {
    float4 v = reinterpret_cast<const float4*>(in)[i];
    ushort4 o;
    o.x = f2bf(v.x); o.y = f2bf(v.y); o.z = f2bf(v.z); o.w = f2bf(v.w);
    reinterpret_cast<ushort4*>(out)[i] = o;
  }
}

// ---------- routing: wave per token, exact fp32 logits ----------
__global__ void routing_kernel(const float* __restrict__ x, const float* __restrict__ gw,
                               float* __restrict__ logits, int* __restrict__ cnt1,
                               int* __restrict__ cnt2, int* __restrict__ tok_e01,
                               float2* __restrict__ tok_w) {
  int lane = threadIdx.x & 63;
  int gwave = (blockIdx.x * blockDim.x + threadIdx.x) >> 6;
  const float4* gw4 = reinterpret_cast<const float4*>(gw);
  for (int j = 0; j < 4; ++j) {
    int t = gwave * 4 + j;
    const float4* xr = reinterpret_cast<const float4*>(x + (size_t)t * HID);
    float acc[NEXP];
#pragma unroll
    for (int e = 0; e < NEXP; ++e) acc[e] = 0.f;
#pragma unroll
    for (int q = 0; q < 4; ++q) {
      float4 xv = xr[lane * 4 + q];
#pragma unroll
      for (int e = 0; e < NEXP; ++e) {
        float4 gv = gw4[e * 256 + lane * 4 + q];
        acc[e] += xv.x * gv.x + xv.y * gv.y + xv.z * gv.z + xv.w * gv.w;
      }
    }
#pragma unroll
    for (int e = 0; e < NEXP; ++e) {
#pragma unroll
      for (int off = 32; off > 0; off >>= 1)
        acc[e] += __shfl_xor(acc[e], off, 64);
    }
    if (lane == 0) {
      // top-2, ties -> lower index (matches jax.lax.top_k)
      int i0 = 0; float m0 = acc[0];
#pragma unroll
      for (int e = 1; e < NEXP; ++e) if (acc[e] > m0) { m0 = acc[e]; i0 = e; }
      int i1 = -1; float m1 = -3.4e38f;
#pragma unroll
      for (int e = 0; e < NEXP; ++e) if (e != i0 && acc[e] > m1) { m1 = acc[e]; i1 = e; }
      float w0 = 1.f / (1.f + expf(m1 - m0));
      float w1 = 1.f - w0;
      atomicAdd(&cnt1[i0], 1);
      atomicAdd(&cnt2[i1], 1);
      tok_e01[t] = i0 | (i1 << 16);
      tok_w[t] = make_float2(w0, w1);
#pragma unroll
      for (int e = 0; e < NEXP; ++e) logits[(size_t)t * NEXP + e] = acc[e];
    }
  }
}

// ---------- schedule build (1 thread; <600 trivial iterations) ----------
__global__ void sched_kernel(const int* __restrict__ cnt1, const int* __restrict__ cnt2,
                             int* __restrict__ off, int4* __restrict__ sched1,
                             int4* __restrict__ sched2a, int4* __restrict__ sched2b,
                             int* __restrict__ nsched) {
  if (threadIdx.x != 0 || blockIdx.x != 0) return;
  int o = 0, s1 = 0, s2a = 0, s2b = 0;
  for (int e = 0; e < NEXP; ++e) {
    int c1 = cnt1[e], c2 = cnt2[e], n = c1 + c2;
    off[e] = o;
    for (int t0 = 0; t0 < n; t0 += 128) {
      int hi = t0 + 128 < n ? t0 + 128 : n;
      sched1[s1++] = make_int4(o + t0, o + hi, e, 0);
    }
    for (int t0 = 0; t0 < c1; t0 += 128) {
      int hi = t0 + 128 < c1 ? t0 + 128 : c1;
      sched2a[s2a++] = make_int4(o + t0, o + hi, e, 0);
    }
    for (int t0 = 0; t0 < c2; t0 += 128) {
      int hi = t0 + 128 < c2 ? t0 + 128 : c2;
      sched2b[s2b++] = make_int4(o + c1 + t0, o + c1 + hi, e, 0);
    }
    o += n;
  }
  nsched[0] = s1; nsched[1] = s2a; nsched[2] = s2b;
}

// ---------- scatter tokens into expert-grouped row lists ----------
__global__ void scatter_kernel(const int* __restrict__ tok_e01, const float2* __restrict__ tok_w,
                               const int* __restrict__ off, const int* __restrict__ cnt1,
                               int* __restrict__ fill0, int* __restrict__ fill1,
                               int* __restrict__ row_token, float* __restrict__ row_weight) {
  int t = blockIdx.x * blockDim.x + threadIdx.x;
  if (t >= T_TOKENS) return;
  int p = tok_e01[t];
  int e0 = p & 0xffff, e1 = p >> 16;
  float2 w = tok_w[t];
  int p0 = off[e0] + atomicAdd(&fill0[e0], 1);
  row_token[p0] = t; row_weight[p0] = w.x;
  int p1 = off[e1] + cnt1[e1] + atomicAdd(&fill1[e1], 1);
  row_token[p1] = t; row_weight[p1] = w.y;
}

// ---------- grouped GEMM, 128x128xBK64, 4 waves, mfma 16x16x32 bf16 ----------
// MODE 0: A = gathered xb rows, epilogue gelu(.+b1) -> h (bf16)
// MODE 1: A = h rows (contiguous), epilogue out[tok] = w*(acc+b2)        (store)
// MODE 2: same but out[tok] += w*(acc+b2)                                 (add)
template <int MODE, int KDIM, int NDIM>
__global__ __launch_bounds__(256) void gemm_kernel(
    const unsigned short* __restrict__ A, const unsigned short* __restrict__ Bw,
    const float* __restrict__ bias, unsigned short* __restrict__ hOut,
    float* __restrict__ out, const int* __restrict__ row_token,
    const float* __restrict__ row_weight, const int4* __restrict__ sched,
    const int* __restrict__ nsched_p, int nsched_idx) {
  int sid = blockIdx.x;
  if (sid >= nsched_p[nsched_idx]) return;
  int4 s = sched[sid];
  const int row_start = s.x, row_limit = s.y, e = s.z;
  const int colBase = blockIdx.y * 128;

  __shared__ __attribute__((aligned(16))) unsigned short As[128 * 64];
  __shared__ __attribute__((aligned(16))) unsigned short Bs[128 * 64];

  const int tid = threadIdx.x;
  const int wave = tid >> 6;
  const int lane = tid & 63;

  // staging source pointers (4 chunks of 32 rows each; 16B per lane per chunk)
  const unsigned short* aSrc[4];
  const unsigned short* bSrc[4];
  const unsigned short* Bbase = Bw + (size_t)e * (2048 * 1024);
  const int kkel = (tid & 7) * 8;
#pragma unroll
  for (int i = 0; i < 4; ++i) {
    int r = (i * 256 + tid) >> 3;  // row in tile [0,128)
    int rg = row_start + r;
    rg = rg < row_limit ? rg : (row_limit - 1);  // clamp partial tiles
    if (MODE == 0) {
      int tok = row_token[rg];
      aSrc[i] = A + (size_t)tok * KDIM + kkel;
    } else {
      aSrc[i] = A + (size_t)rg * KDIM + kkel;
    }
    bSrc[i] = Bbase + (size_t)(colBase + r) * KDIM + kkel;
  }
  char* AsB = (char*)As;
  char* BsB = (char*)Bs;

  f32x4 zero = {0.f, 0.f, 0.f, 0.f};
  f32x4 acc[4][4];
#pragma unroll
  for (int m = 0; m < 4; ++m)
#pragma unroll
    for (int n = 0; n < 4; ++n) acc[m][n] = zero;

  const int aRow = (wave >> 1) * 64 + (lane & 15);
  const int bRow = (wave & 1) * 64 + (lane & 15);
  const int kB = (lane >> 4) * 16;  // byte offset of this lane's 8 bf16 within 32-K slice

  for (int kt = 0; kt < KDIM / 64; ++kt) {
    const size_t koff = (size_t)kt * 128;  // 64 bf16 = 128 bytes
#pragma unroll
    for (int i = 0; i < 4; ++i) {
      async16((const char*)aSrc[i] + koff, AsB + (i * 4 + wave) * 1024);
      async16((const char*)bSrc[i] + koff, BsB + (i * 4 + wave) * 1024);
    }
    __syncthreads();  // compiler drains vmcnt(0) before s_barrier
#pragma unroll
    for (int ks = 0; ks < 2; ++ks) {
      bf16x8 af[4], bf[4];
#pragma unroll
      for (int m = 0; m < 4; ++m)
        af[m] = *reinterpret_cast<const bf16x8*>(AsB + (aRow + m * 16) * 128 + ks * 64 + kB);
#pragma unroll
      for (int n = 0; n < 4; ++n)
        bf[n] = *reinterpret_cast<const bf16x8*>(BsB + (bRow + n * 16) * 128 + ks * 64 + kB);
#pragma unroll
      for (int m = 0; m < 4; ++m)
#pragma unroll
        for (int n = 0; n < 4; ++n)
          acc[m][n] = __builtin_amdgcn_mfma_f32_16x16x32_bf16(af[m], bf[n], acc[m][n], 0, 0, 0);
    }
    __syncthreads();
  }

  // epilogue: C/D mapping col=lane&15, row=(lane>>4)*4+reg (m89/m91-verified)
  const int cCol = lane & 15;
  const int cRowB = (lane >> 4) * 4;
  const int wrBase = (wave >> 1) * 64;
  const int wcBase = (wave & 1) * 64;

  if (MODE == 0) {
#pragma unroll
    for (int n = 0; n < 4; ++n) {
      int col = colBase + wcBase + n * 16 + cCol;
      float bb = bias[e * NDIM + col];
#pragma unroll
      for (int m = 0; m < 4; ++m) {
#pragma unroll
        for (int j = 0; j < 4; ++j) {
          int r = row_start + wrBase + m * 16 + cRowB + j;
          if (r < row_limit) {
            float v = acc[m][n][j] + bb;
            v = 0.5f * v * (1.f + erff(v * 0.70710678118654752f));  // exact gelu
            hOut[(size_t)r * NDIM + col] = f2bf(v);
          }
        }
      }
    }
  } else {
#pragma unroll
    for (int m = 0; m < 4; ++m) {
#pragma unroll
      for (int j = 0; j < 4; ++j) {
        int rr = row_start + wrBase + m * 16 + cRowB + j;
        if (rr < row_limit) {
          int tok = row_token[rr];
          float wgt = row_weight[rr];
          float* orow = out + (size_t)tok * NDIM;
#pragma unroll
          for (int n = 0; n < 4; ++n) {
            int col = colBase + wcBase + n * 16 + cCol;
            float v = wgt * (acc[m][n][j] + bias[e * NDIM + col]);
            if (MODE == 2) v += orow[col];  // pass A completed (stream order)
            orow[col] = v;
          }
        }
      }
    }
  }
}

// ---------- launch ----------
extern "C" void kernel_launch(void* const* d_in, const int* in_sizes, int n_in,
                              void* d_out, int out_size, void* d_ws, size_t ws_size,
                              hipStream_t stream) {
  const float* x  = (const float*)d_in[0];
  const float* gw = (const float*)d_in[1];
  const float* w1 = (const float*)d_in[2];
  const float* b1 = (const float*)d_in[3];
  const float* w2 = (const float*)d_in[4];
  const float* b2 = (const float*)d_in[5];
  float* out = (float*)d_out;
  float* logits = out + (size_t)T_TOKENS * HID;

  char* ws = (char*)d_ws;
  // --- small metadata (first 256 B zeroed each call) ---
  int* cnt1 = (int*)ws;        // 8
  int* cnt2 = cnt1 + 8;        // 8
  int* fill0 = cnt1 + 16;      // 8
  int* fill1 = cnt1 + 24;      // 8
  int* nsched = cnt1 + 32;     // 3
  int* off = (int*)(ws + 256); // 8
  int4* sched1  = (int4*)(ws + 512);           // <=264 entries
  int4* sched2a = (int4*)(ws + 512 + 4352);    // <=136
  int4* sched2b = (int4*)(ws + 512 + 4352 + 2304);
  int* tok_e01 = (int*)(ws + 16384);                       // 64 KB
  float2* tok_w = (float2*)(ws + 16384 + 65536);           // 128 KB
  int* row_token = (int*)(ws + 16384 + 65536 + 131072);    // 128 KB
  float* row_weight = (float*)(ws + 16384 + 65536 + 2 * 131072);  // 128 KB
  const size_t BIG = 1u << 20;
  unsigned short* xb  = (unsigned short*)(ws + BIG);         // 32 MiB
  unsigned short* w1b = xb  + (size_t)16777216;              // 32 MiB
  unsigned short* w2b = w1b + (size_t)16777216;              // 32 MiB
  unsigned short* h   = w2b + (size_t)16777216;              // 128 MiB
  const size_t REQUIRED = BIG + 3ull * 33554432ull + 134217728ull;
  if (ws_size < REQUIRED) return;  // distinguishable failure: output stays poison

  hipMemsetAsync(d_ws, 0, 256, stream);
  cast_bf16_kernel<<<2048, 256, 0, stream>>>(x,  xb,  16777216);
  cast_bf16_kernel<<<2048, 256, 0, stream>>>(w1, w1b, 16777216);
  cast_bf16_kernel<<<2048, 256, 0, stream>>>(w2, w2b, 16777216);
  routing_kernel<<<1024, 256, 0, stream>>>(x, gw, logits, cnt1, cnt2, tok_e01, tok_w);
  sched_kernel<<<1, 64, 0, stream>>>(cnt1, cnt2, off, sched1, sched2a, sched2b, nsched);
  scatter_kernel<<<64, 256, 0, stream>>>(tok_e01, tok_w, off, cnt1, fill0, fill1,
                                         row_token, row_weight);
  // GEMM1: h = gelu(x @ w1^T + b1), rows = all 2T assignments grouped by expert
  gemm_kernel<0, 1024, 2048><<<dim3(264, 16), 256, 0, stream>>>(
      xb, w1b, b1, h, nullptr, row_token, nullptr, sched1, nsched, 0);
  // GEMM2 pass A (slot-0 rows, plain store) then pass B (slot-1 rows, add)
  gemm_kernel<1, 2048, 1024><<<dim3(136, 8), 256, 0, stream>>>(
      h, w2b, b2, nullptr, out, row_token, row_weight, sched2a, nsched, 1);
  gemm_kernel<2, 2048, 1024><<<dim3(136, 8), 256, 0, stream>>>(
      h, w2b, b2, nullptr, out, row_token, row_weight, sched2b, nsched, 2);
}

// Round 2
// 1357.218 us; speedup vs baseline: 1.0023x; 1.0023x over previous
//
#include <hip/hip_runtime.h>
#include <stdint.h>

#define T_TOKENS 16384
#define HID 1024
#define INTERM 2048
#define NEXP 8

typedef __bf16 bf16x8 __attribute__((ext_vector_type(8)));
typedef float f32x4 __attribute__((ext_vector_type(4)));

// ---------- helpers ----------
__device__ __forceinline__ unsigned short f2bf(float f) {
  union { float f; uint32_t u; } v; v.f = f;
  uint32_t u = v.u + 0x7fffu + ((v.u >> 16) & 1u);
  return (unsigned short)(u >> 16);
}

__device__ __forceinline__ void async16(const void* g, void* l) {
  // CK idiom: generic->AS1/AS3 via uintptr_t (LDS generic addr low 32 bits == ds offset)
  auto gp = (const __attribute__((address_space(1))) uint32_t*)(uintptr_t)g;
  auto lp = (__attribute__((address_space(3))) uint32_t*)(uintptr_t)l;
  __builtin_amdgcn_global_load_lds(gp, lp, 16, 0, 0);
}

// ---------- fp32 -> bf16 cast ----------
__global__ void cast_bf16_kernel(const float* __restrict__ in,
                                 unsigned short* __restrict__ out, int n) {
  int stride = gridDim.x * blockDim.x;
  for (int i = blockIdx.x * blockDim.x + threadIdx.x; i < (n >> 2); i += stride) {
    float4 v = reinterpret_cast<const float4*>(in)[i];
    ushort4 o;
    o.x = f2bf(v.x); o.y = f2bf(v.y); o.z = f2bf(v.z); o.w = f2bf(v.w);
    reinterpret_cast<ushort4*>(out)[i] = o;
  }
}

// ---------- routing: wave per token, exact fp32 logits ----------
__global__ void routing_kernel(const float* __restrict__ x, const float* __restrict__ gw,
                               float* __restrict__ logits, int* __restrict__ cnt1,
                               int* __restrict__ cnt2, int* __restrict__ tok_e01,
                               float2* __restrict__ tok_w) {
  int lane = threadIdx.x & 63;
  int gwave = (blockIdx.x * blockDim.x + threadIdx.x) >> 6;
  const float4* gw4 = reinterpret_cast<const float4*>(gw);
  for (int j = 0; j < 4; ++j) {
    int t = gwave * 4 + j;
    const float4* xr = reinterpret_cast<const float4*>(x + (size_t)t * HID);
    float acc[NEXP];
#pragma unroll
    for (int e = 0; e < NEXP; ++e) acc[e] = 0.f;
#pragma unroll
    for (int q = 0; q < 4; ++q) {
      float4 xv = xr[lane * 4 + q];
#pragma unroll
      for (int e = 0; e < NEXP; ++e) {
        float4 gv = gw4[e * 256 + lane * 4 + q];
        acc[e] += xv.x * gv.x + xv.y * gv.y + xv.z * gv.z + xv.w * gv.w;
      }
    }
#pragma unroll
    for (int e = 0; e < NEXP; ++e) {
#pragma unroll
      for (int off = 32; off > 0; off >>= 1)
        acc[e] += __shfl_xor(acc[e], off, 64);
    }
    if (lane == 0) {
      // top-2, ties -> lower index (matches jax.lax.top_k)
      int i0 = 0; float m0 = acc[0];
#pragma unroll
      for (int e = 1; e < NEXP; ++e) if (acc[e] > m0) { m0 = acc[e]; i0 = e; }
      int i1 = -1; float m1 = -3.4e38f;
#pragma unroll
      for (int e = 0; e < NEXP; ++e) if (e != i0 && acc[e] > m1) { m1 = acc[e]; i1 = e; }
      float w0 = 1.f / (1.f + expf(m1 - m0));
      float w1 = 1.f - w0;
      atomicAdd(&cnt1[i0], 1);
      atomicAdd(&cnt2[i1], 1);
      tok_e01[t] = i0 | (i1 << 16);
      tok_w[t] = make_float2(w0, w1);
#pragma unroll
      for (int e = 0; e < NEXP; ++e) logits[(size_t)t * NEXP + e] = acc[e];
    }
  }
}

// ---------- schedule build (1 thread; <600 trivial iterations) ----------
__global__ void sched_kernel(const int* __restrict__ cnt1, const int* __restrict__ cnt2,
                             int* __restrict__ off, int4* __restrict__ sched1,
                             int4* __restrict__ sched2a, int4* __restrict__ sched2b,
                             int* __restrict__ nsched) {
  if (threadIdx.x != 0 || blockIdx.x != 0) return;
  int o = 0, s1 = 0, s2a = 0, s2b = 0;
  for (int e = 0; e < NEXP; ++e) {
    int c1 = cnt1[e], c2 = cnt2[e], n = c1 + c2;
    off[e] = o;
    for (int t0 = 0; t0 < n; t0 += 128) {
      int hi = t0 + 128 < n ? t0 + 128 : n;
      sched1[s1++] = make_int4(o + t0, o + hi, e, 0);
    }
    for (int t0 = 0; t0 < c1; t0 += 128) {
      int hi = t0 + 128 < c1 ? t0 + 128 : c1;
      sched2a[s2a++] = make_int4(o + t0, o + hi, e, 0);
    }
    for (int t0 = 0; t0 < c2; t0 += 128) {
      int hi = t0 + 128 < c2 ? t0 + 128 : c2;
      sched2b[s2b++] = make_int4(o + c1 + t0, o + c1 + hi, e, 0);
    }
    o += n;
  }
  nsched[0] = s1; nsched[1] = s2a; nsched[2] = s2b;
}

// ---------- scatter tokens into expert-grouped row lists ----------
__global__ void scatter_kernel(const int* __restrict__ tok_e01, const float2* __restrict__ tok_w,
                               const int* __restrict__ off, const int* __restrict__ cnt1,
                               int* __restrict__ fill0, int* __restrict__ fill1,
                               int* __restrict__ row_token, float* __restrict__ row_weight) {
  int t = blockIdx.x * blockDim.x + threadIdx.x;
  if (t >= T_TOKENS) return;
  int p = tok_e01[t];
  int e0 = p & 0xffff, e1 = p >> 16;
  float2 w = tok_w[t];
  int p0 = off[e0] + atomicAdd(&fill0[e0], 1);
  row_token[p0] = t; row_weight[p0] = w.x;
  int p1 = off[e1] + cnt1[e1] + atomicAdd(&fill1[e1], 1);
  row_token[p1] = t; row_weight[p1] = w.y;
}

// ---------- grouped GEMM, 128x128xBK64, 4 waves, mfma 16x16x32 bf16 ----------
// MODE 0: A = gathered xb rows, epilogue gelu(.+b1) -> h (bf16)
// MODE 1: A = h rows (contiguous), epilogue out[tok] = w*(acc+b2)        (store)
// MODE 2: same but out[tok] += w*(acc+b2)                                 (add)
template <int MODE, int KDIM, int NDIM>
__global__ __launch_bounds__(256) void gemm_kernel(
    const unsigned short* __restrict__ A, const unsigned short* __restrict__ Bw,
    const float* __restrict__ bias, unsigned short* __restrict__ hOut,
    float* __restrict__ out, const int* __restrict__ row_token,
    const float* __restrict__ row_weight, const int4* __restrict__ sched,
    const int* __restrict__ nsched_p, int nsched_idx) {
  int sid = blockIdx.x;
  if (sid >= nsched_p[nsched_idx]) return;
  int4 s = sched[sid];
  const int row_start = s.x, row_limit = s.y, e = s.z;
  const int colBase = blockIdx.y * 128;

  __shared__ __attribute__((aligned(16))) unsigned short As[128 * 64];
  __shared__ __attribute__((aligned(16))) unsigned short Bs[128 * 64];

  const int tid = threadIdx.x;
  const int wave = tid >> 6;
  const int lane = tid & 63;

  // staging source pointers (4 chunks of 32 rows each; 16B per lane per chunk)
  const unsigned short* aSrc[4];
  const unsigned short* bSrc[4];
  const unsigned short* Bbase = Bw + (size_t)e * (2048 * 1024);
  const int kkel = (tid & 7) * 8;
#pragma unroll
  for (int i = 0; i < 4; ++i) {
    int r = (i * 256 + tid) >> 3;  // row in tile [0,128)
    int rg = row_start + r;
    rg = rg < row_limit ? rg : (row_limit - 1);  // clamp partial tiles
    if (MODE == 0) {
      int tok = row_token[rg];
      aSrc[i] = A + (size_t)tok * KDIM + kkel;
    } else {
      aSrc[i] = A + (size_t)rg * KDIM + kkel;
    }
    bSrc[i] = Bbase + (size_t)(colBase + r) * KDIM + kkel;
  }
  char* AsB = (char*)As;
  char* BsB = (char*)Bs;

  f32x4 zero = {0.f, 0.f, 0.f, 0.f};
  f32x4 acc[4][4];
#pragma unroll
  for (int m = 0; m < 4; ++m)
#pragma unroll
    for (int n = 0; n < 4; ++n) acc[m][n] = zero;

  const int aRow = (wave >> 1) * 64 + (lane & 15);
  const int bRow = (wave & 1) * 64 + (lane & 15);
  const int kB = (lane >> 4) * 16;  // byte offset of this lane's 8 bf16 within 32-K slice

  for (int kt = 0; kt < KDIM / 64; ++kt) {
    const size_t koff = (size_t)kt * 128;  // 64 bf16 = 128 bytes
#pragma unroll
    for (int i = 0; i < 4; ++i) {
      async16((const char*)aSrc[i] + koff, AsB + (i * 4 + wave) * 1024);
      async16((const char*)bSrc[i] + koff, BsB + (i * 4 + wave) * 1024);
    }
    __syncthreads();  // compiler drains vmcnt(0) before s_barrier
#pragma unroll
    for (int ks = 0; ks < 2; ++ks) {
      bf16x8 af[4], bf[4];
#pragma unroll
      for (int m = 0; m < 4; ++m)
        af[m] = *reinterpret_cast<const bf16x8*>(AsB + (aRow + m * 16) * 128 + ks * 64 + kB);
#pragma unroll
      for (int n = 0; n < 4; ++n)
        bf[n] = *reinterpret_cast<const bf16x8*>(BsB + (bRow + n * 16) * 128 + ks * 64 + kB);
#pragma unroll
      for (int m = 0; m < 4; ++m)
#pragma unroll
        for (int n = 0; n < 4; ++n)
          acc[m][n] = __builtin_amdgcn_mfma_f32_16x16x32_bf16(af[m], bf[n], acc[m][n], 0, 0, 0);
    }
    __syncthreads();
  }

  // epilogue: C/D mapping col=lane&15, row=(lane>>4)*4+reg (m89/m91-verified)
  const int cCol = lane & 15;
  const int cRowB = (lane >> 4) * 4;
  const int wrBase = (wave >> 1) * 64;
  const int wcBase = (wave & 1) * 64;

  if (MODE == 0) {
#pragma unroll
    for (int n = 0; n < 4; ++n) {
      int col = colBase + wcBase + n * 16 + cCol;
      float bb = bias[e * NDIM + col];
#pragma unroll
      for (int m = 0; m < 4; ++m) {
#pragma unroll
        for (int j = 0; j < 4; ++j) {
          int r = row_start + wrBase + m * 16 + cRowB + j;
          if (r < row_limit) {
            float v = acc[m][n][j] + bb;
            v = 0.5f * v * (1.f + erff(v * 0.70710678118654752f));  // exact gelu
            hOut[(size_t)r * NDIM + col] = f2bf(v);
          }
        }
      }
    }
  } else {
#pragma unroll
    for (int m = 0; m < 4; ++m) {
#pragma unroll
      for (int j = 0; j < 4; ++j) {
        int rr = row_start + wrBase + m * 16 + cRowB + j;
        if (rr < row_limit) {
          int tok = row_token[rr];
          float wgt = row_weight[rr];
          float* orow = out + (size_t)tok * NDIM;
#pragma unroll
          for (int n = 0; n < 4; ++n) {
            int col = colBase + wcBase + n * 16 + cCol;
            float v = wgt * (acc[m][n][j] + bias[e * NDIM + col]);
            if (MODE == 2) v += orow[col];  // pass A completed (stream order)
            orow[col] = v;
          }
        }
      }
    }
  }
}

// ---------- launch ----------
extern "C" void kernel_launch(void* const* d_in, const int* in_sizes, int n_in,
                              void* d_out, int out_size, void* d_ws, size_t ws_size,
                              hipStream_t stream) {
  const float* x  = (const float*)d_in[0];
  const float* gw = (const float*)d_in[1];
  const float* w1 = (const float*)d_in[2];
  const float* b1 = (const float*)d_in[3];
  const float* w2 = (const float*)d_in[4];
  const float* b2 = (const float*)d_in[5];
  float* out = (float*)d_out;
  float* logits = out + (size_t)T_TOKENS * HID;

  char* ws = (char*)d_ws;
  // --- small metadata (first 256 B zeroed each call) ---
  int* cnt1 = (int*)ws;        // 8
  int* cnt2 = cnt1 + 8;        // 8
  int* fill0 = cnt1 + 16;      // 8
  int* fill1 = cnt1 + 24;      // 8
  int* nsched = cnt1 + 32;     // 3
  int* off = (int*)(ws + 256); // 8
  int4* sched1  = (int4*)(ws + 512);           // <=264 entries
  int4* sched2a = (int4*)(ws + 512 + 4352);    // <=136
  int4* sched2b = (int4*)(ws + 512 + 4352 + 2304);
  int* tok_e01 = (int*)(ws + 16384);                       // 64 KB
  float2* tok_w = (float2*)(ws + 16384 + 65536);           // 128 KB
  int* row_token = (int*)(ws + 16384 + 65536 + 131072);    // 128 KB
  float* row_weight = (float*)(ws + 16384 + 65536 + 2 * 131072);  // 128 KB
  const size_t BIG = 1u << 20;
  unsigned short* xb  = (unsigned short*)(ws + BIG);         // 32 MiB
  unsigned short* w1b = xb  + (size_t)16777216;              // 32 MiB
  unsigned short* w2b = w1b + (size_t)16777216;              // 32 MiB
  unsigned short* h   = w2b + (size_t)16777216;              // 128 MiB
  const size_t REQUIRED = BIG + 3ull * 33554432ull + 134217728ull;
  if (ws_size < REQUIRED) return;  // distinguishable failure: output stays poison

  hipMemsetAsync(d_ws, 0, 256, stream);
  cast_bf16_kernel<<<2048, 256, 0, stream>>>(x,  xb,  16777216);
  cast_bf16_kernel<<<2048, 256, 0, stream>>>(w1, w1b, 16777216);
  cast_bf16_kernel<<<2048, 256, 0, stream>>>(w2, w2b, 16777216);
  routing_kernel<<<1024, 256, 0, stream>>>(x, gw, logits, cnt1, cnt2, tok_e01, tok_w);
  sched_kernel<<<1, 64, 0, stream>>>(cnt1, cnt2, off, sched1, sched2a, sched2b, nsched);
  scatter_kernel<<<64, 256, 0, stream>>>(tok_e01, tok_w, off, cnt1, fill0, fill1,
                                         row_token, row_weight);
  // GEMM1: h = gelu(x @ w1^T + b1), rows = all 2T assignments grouped by expert
  gemm_kernel<0, 1024, 2048><<<dim3(264, 16), 256, 0, stream>>>(
      xb, w1b, b1, h, nullptr, row_token, nullptr, sched1, nsched, 0);
  // GEMM2 pass A (slot-0 rows, plain store) then pass B (slot-1 rows, add)
  gemm_kernel<1, 2048, 1024><<<dim3(136, 8), 256, 0, stream>>>(
      h, w2b, b2, nullptr, out, row_token, row_weight, sched2a, nsched, 1);
  gemm_kernel<2, 2048, 1024><<<dim3(136, 8), 256, 0, stream>>>(
      h, w2b, b2, nullptr, out, row_token, row_weight, sched2b, nsched, 2);
}

// Round 3
// 1179.706 us; speedup vs baseline: 1.1531x; 1.1505x over previous
//
#include <hip/hip_runtime.h>
#include <stdint.h>

#define T_TOKENS 16384
#define HID 1024
#define INTERM 2048
#define NEXP 8

typedef __bf16 bf16x8 __attribute__((ext_vector_type(8)));
typedef float f32x4 __attribute__((ext_vector_type(4)));

// ---------- helpers ----------
__device__ __forceinline__ unsigned short f2bf(float f) {
  union { float f; uint32_t u; } v; v.f = f;
  uint32_t u = v.u + 0x7fffu + ((v.u >> 16) & 1u);
  return (unsigned short)(u >> 16);
}

__device__ __forceinline__ void async16(const void* g, void* l) {
  auto gp = (const __attribute__((address_space(1))) uint32_t*)(uintptr_t)g;
  auto lp = (__attribute__((address_space(3))) uint32_t*)(uintptr_t)l;
  __builtin_amdgcn_global_load_lds(gp, lp, 16, 0, 0);
}

// tanh-form gelu via fast exp: max abs err ~3e-4 vs exact erf-gelu
__device__ __forceinline__ float gelu_fast(float v) {
  float s = 1.5957691216f * v + 0.0713548163f * v * v * v;  // 2*0.79788456*(v+0.044715 v^3)
  return v / (1.f + __expf(-s));
}

// ---------- fp32 -> bf16 cast (weights) ----------
__global__ void cast_bf16_kernel(const float* __restrict__ in,
                                 unsigned short* __restrict__ out, int n) {
  int stride = gridDim.x * blockDim.x;
  for (int i = blockIdx.x * blockDim.x + threadIdx.x; i < (n >> 2); i += stride) {
    float4 v = reinterpret_cast<const float4*>(in)[i];
    ushort4 o;
    o.x = f2bf(v.x); o.y = f2bf(v.y); o.z = f2bf(v.z); o.w = f2bf(v.w);
    reinterpret_cast<ushort4*>(out)[i] = o;
  }
}

// ---------- routing: coalesced wave-per-token, gw in LDS, fused x->bf16 cast ----------
__global__ __launch_bounds__(256) void routing_kernel(
    const float* __restrict__ x, const float* __restrict__ gw,
    float* __restrict__ logits, unsigned short* __restrict__ xb,
    int* __restrict__ cnt1, int* __restrict__ cnt2,
    int* __restrict__ tok_e01, float2* __restrict__ tok_w) {
  __shared__ float4 gws[2048];  // 8 experts x 1024 floats = 32 KB
  const int tid = threadIdx.x;
  for (int i = tid; i < 2048; i += 256)
    gws[i] = reinterpret_cast<const float4*>(gw)[i];
  __syncthreads();

  const int lane = tid & 63;
  const int wave = tid >> 6;
  const int tbase = blockIdx.x * 32 + wave * 8;  // 512 blocks * 32 tokens
  for (int j = 0; j < 8; ++j) {
    int t = tbase + j;
    const float4* xr = reinterpret_cast<const float4*>(x + (size_t)t * HID);
    float4 xv[4];
#pragma unroll
    for (int q = 0; q < 4; ++q) xv[q] = xr[q * 64 + lane];  // coalesced 1KB/instr
    // fused cast: write bf16 row of x
    ushort4* xbr = reinterpret_cast<ushort4*>(xb + (size_t)t * HID);
#pragma unroll
    for (int q = 0; q < 4; ++q) {
      ushort4 o;
      o.x = f2bf(xv[q].x); o.y = f2bf(xv[q].y);
      o.z = f2bf(xv[q].z); o.w = f2bf(xv[q].w);
      xbr[q * 64 + lane] = o;
    }
    float acc[NEXP];
#pragma unroll
    for (int e = 0; e < NEXP; ++e) {
      float a = 0.f;
#pragma unroll
      for (int q = 0; q < 4; ++q) {
        float4 g = gws[e * 256 + q * 64 + lane];
        a += xv[q].x * g.x + xv[q].y * g.y + xv[q].z * g.z + xv[q].w * g.w;
      }
      acc[e] = a;
    }
#pragma unroll
    for (int e = 0; e < NEXP; ++e)
#pragma unroll
      for (int off = 32; off > 0; off >>= 1)
        acc[e] += __shfl_xor(acc[e], off, 64);
    if (lane == 0) {
      int i0 = 0; float m0 = acc[0];
#pragma unroll
      for (int e = 1; e < NEXP; ++e) if (acc[e] > m0) { m0 = acc[e]; i0 = e; }
      int i1 = -1; float m1 = -3.4e38f;
#pragma unroll
      for (int e = 0; e < NEXP; ++e) if (e != i0 && acc[e] > m1) { m1 = acc[e]; i1 = e; }
      float w0 = 1.f / (1.f + expf(m1 - m0));
      float w1 = 1.f - w0;
      atomicAdd(&cnt1[i0], 1);
      atomicAdd(&cnt2[i1], 1);
      tok_e01[t] = i0 | (i1 << 16);
      tok_w[t] = make_float2(w0, w1);
      float4* lg = reinterpret_cast<float4*>(logits + (size_t)t * NEXP);
      lg[0] = make_float4(acc[0], acc[1], acc[2], acc[3]);
      lg[1] = make_float4(acc[4], acc[5], acc[6], acc[7]);
    }
  }
}

// ---------- schedule build ----------
__global__ void sched_kernel(const int* __restrict__ cnt1, const int* __restrict__ cnt2,
                             int* __restrict__ off, int4* __restrict__ sched1,
                             int4* __restrict__ sched2a, int4* __restrict__ sched2b,
                             int* __restrict__ nsched) {
  if (threadIdx.x != 0 || blockIdx.x != 0) return;
  int o = 0, s1 = 0, s2a = 0, s2b = 0;
  for (int e = 0; e < NEXP; ++e) {
    int c1 = cnt1[e], c2 = cnt2[e], n = c1 + c2;
    off[e] = o;
    for (int t0 = 0; t0 < n; t0 += 128) {
      int hi = t0 + 128 < n ? t0 + 128 : n;
      sched1[s1++] = make_int4(o + t0, o + hi, e, 0);
    }
    for (int t0 = 0; t0 < c1; t0 += 128) {
      int hi = t0 + 128 < c1 ? t0 + 128 : c1;
      sched2a[s2a++] = make_int4(o + t0, o + hi, e, 0);
    }
    for (int t0 = 0; t0 < c2; t0 += 128) {
      int hi = t0 + 128 < c2 ? t0 + 128 : c2;
      sched2b[s2b++] = make_int4(o + c1 + t0, o + c1 + hi, e, 0);
    }
    o += n;
  }
  nsched[0] = s1; nsched[1] = s2a; nsched[2] = s2b;
}

// ---------- scatter tokens into expert-grouped row lists ----------
__global__ void scatter_kernel(const int* __restrict__ tok_e01, const float2* __restrict__ tok_w,
                               const int* __restrict__ off, const int* __restrict__ cnt1,
                               int* __restrict__ fill0, int* __restrict__ fill1,
                               int* __restrict__ row_token, float* __restrict__ row_weight) {
  int t = blockIdx.x * blockDim.x + threadIdx.x;
  if (t >= T_TOKENS) return;
  int p = tok_e01[t];
  int e0 = p & 0xffff, e1 = p >> 16;
  float2 w = tok_w[t];
  int p0 = off[e0] + atomicAdd(&fill0[e0], 1);
  row_token[p0] = t; row_weight[p0] = w.x;
  int p1 = off[e1] + cnt1[e1] + atomicAdd(&fill1[e1], 1);
  row_token[p1] = t; row_weight[p1] = w.y;
}

// ---------- grouped GEMM, 128x128xBK64, 4 waves, 2-phase double-buffered ----------
// MODE 0: A = gathered xb rows, epilogue gelu(.+b1) -> h (bf16)
// MODE 1: A = h rows (contiguous), epilogue out[tok] = w*(acc+b2)   (store)
// MODE 2: same but out[tok] += w*(acc+b2)                            (add)
template <int MODE, int KDIM, int NDIM>
__global__ __launch_bounds__(256) void gemm_kernel(
    const unsigned short* __restrict__ A, const unsigned short* __restrict__ Bw,
    const float* __restrict__ bias, unsigned short* __restrict__ hOut,
    float* __restrict__ out, const int* __restrict__ row_token,
    const float* __restrict__ row_weight, const int4* __restrict__ sched,
    const int* __restrict__ nsched_p, int nsched_idx) {
  const int sid = blockIdx.y;  // col-blocks launch-adjacent -> A-tile L2 reuse
  if (sid >= nsched_p[nsched_idx]) return;
  int4 s = sched[sid];
  const int row_start = s.x, row_limit = s.y, e = s.z;
  const int colBase = blockIdx.x * 128;

  // double-buffered: 2 x (16 KB A + 16 KB B) = 64 KB
  __shared__ __attribute__((aligned(16))) unsigned short As[2][128 * 64];
  __shared__ __attribute__((aligned(16))) unsigned short Bs[2][128 * 64];

  const int tid = threadIdx.x;
  const int wave = tid >> 6;
  const int lane = tid & 63;

  const unsigned short* aSrc[4];
  const unsigned short* bSrc[4];
  const unsigned short* Bbase = Bw + (size_t)e * (2048 * 1024);
  const int kkel = (tid & 7) * 8;
#pragma unroll
  for (int i = 0; i < 4; ++i) {
    int r = (i * 256 + tid) >> 3;  // row in tile [0,128)
    int rg = row_start + r;
    rg = rg < row_limit ? rg : (row_limit - 1);  // clamp partial tiles
    if (MODE == 0) {
      int tok = row_token[rg];
      aSrc[i] = A + (size_t)tok * KDIM + kkel;
    } else {
      aSrc[i] = A + (size_t)rg * KDIM + kkel;
    }
    bSrc[i] = Bbase + (size_t)(colBase + r) * KDIM + kkel;
  }

  f32x4 zero = {0.f, 0.f, 0.f, 0.f};
  f32x4 acc[4][4];
#pragma unroll
  for (int m = 0; m < 4; ++m)
#pragma unroll
    for (int n = 0; n < 4; ++n) acc[m][n] = zero;

  const int aRow = (wave >> 1) * 64 + (lane & 15);
  const int bRow = (wave & 1) * 64 + (lane & 15);
  const int kB = (lane >> 4) * 16;
  const int NT = KDIM / 64;

  auto stage = [&](int buf, int kt) {
    const size_t koff = (size_t)kt * 128;  // 64 bf16 = 128 B
    char* AsB = (char*)As[buf];
    char* BsB = (char*)Bs[buf];
#pragma unroll
    for (int i = 0; i < 4; ++i) {
      async16((const char*)aSrc[i] + koff, AsB + (i * 4 + wave) * 1024);
      async16((const char*)bSrc[i] + koff, BsB + (i * 4 + wave) * 1024);
    }
  };
  auto compute = [&](int buf) {
    const char* AsB = (const char*)As[buf];
    const char* BsB = (const char*)Bs[buf];
#pragma unroll
    for (int ks = 0; ks < 2; ++ks) {
      bf16x8 af[4], bfr[4];
#pragma unroll
      for (int m = 0; m < 4; ++m)
        af[m] = *reinterpret_cast<const bf16x8*>(AsB + (aRow + m * 16) * 128 + ks * 64 + kB);
#pragma unroll
      for (int n = 0; n < 4; ++n)
        bfr[n] = *reinterpret_cast<const bf16x8*>(BsB + (bRow + n * 16) * 128 + ks * 64 + kB);
#pragma unroll
      for (int m = 0; m < 4; ++m)
#pragma unroll
        for (int n = 0; n < 4; ++n)
          acc[m][n] = __builtin_amdgcn_mfma_f32_16x16x32_bf16(af[m], bfr[n], acc[m][n], 0, 0, 0);
    }
  };

  // T3-minimum 2-phase: STAGE(next) before compute(cur); one vmcnt-drain/barrier per tile
  stage(0, 0);
  __syncthreads();  // compiler drains vmcnt(0) before s_barrier
  int cur = 0;
  for (int kt = 0; kt < NT - 1; ++kt) {
    stage(cur ^ 1, kt + 1);  // loads fly under the MFMAs below
    compute(cur);
    __syncthreads();
    cur ^= 1;
  }
  compute(cur);  // epilogue tile, no prefetch

  // epilogue: C/D mapping col=lane&15, row=(lane>>4)*4+reg
  const int cCol = lane & 15;
  const int cRowB = (lane >> 4) * 4;
  const int wrBase = (wave >> 1) * 64;
  const int wcBase = (wave & 1) * 64;

  if (MODE == 0) {
#pragma unroll
    for (int n = 0; n < 4; ++n) {
      int col = colBase + wcBase + n * 16 + cCol;
      float bb = bias[e * NDIM + col];
#pragma unroll
      for (int m = 0; m < 4; ++m) {
#pragma unroll
        for (int j = 0; j < 4; ++j) {
          int r = row_start + wrBase + m * 16 + cRowB + j;
          if (r < row_limit) {
            float v = gelu_fast(acc[m][n][j] + bb);
            hOut[(size_t)r * NDIM + col] = f2bf(v);
          }
        }
      }
    }
  } else {
#pragma unroll
    for (int m = 0; m < 4; ++m) {
#pragma unroll
      for (int j = 0; j < 4; ++j) {
        int rr = row_start + wrBase + m * 16 + cRowB + j;
        if (rr < row_limit) {
          int tok = row_token[rr];
          float wgt = row_weight[rr];
          float* orow = out + (size_t)tok * NDIM;
#pragma unroll
          for (int n = 0; n < 4; ++n) {
            int col = colBase + wcBase + n * 16 + cCol;
            float v = wgt * (acc[m][n][j] + bias[e * NDIM + col]);
            if (MODE == 2) v += orow[col];  // pass A completed (stream order)
            orow[col] = v;
          }
        }
      }
    }
  }
}

// ---------- launch ----------
extern "C" void kernel_launch(void* const* d_in, const int* in_sizes, int n_in,
                              void* d_out, int out_size, void* d_ws, size_t ws_size,
                              hipStream_t stream) {
  const float* x  = (const float*)d_in[0];
  const float* gw = (const float*)d_in[1];
  const float* w1 = (const float*)d_in[2];
  const float* b1 = (const float*)d_in[3];
  const float* w2 = (const float*)d_in[4];
  const float* b2 = (const float*)d_in[5];
  float* out = (float*)d_out;
  float* logits = out + (size_t)T_TOKENS * HID;

  char* ws = (char*)d_ws;
  int* cnt1 = (int*)ws;        // 8
  int* cnt2 = cnt1 + 8;        // 8
  int* fill0 = cnt1 + 16;      // 8
  int* fill1 = cnt1 + 24;      // 8
  int* nsched = cnt1 + 32;     // 3
  int* off = (int*)(ws + 256); // 8
  int4* sched1  = (int4*)(ws + 512);
  int4* sched2a = (int4*)(ws + 512 + 4352);
  int4* sched2b = (int4*)(ws + 512 + 4352 + 2304);
  int* tok_e01 = (int*)(ws + 16384);
  float2* tok_w = (float2*)(ws + 16384 + 65536);
  int* row_token = (int*)(ws + 16384 + 65536 + 131072);
  float* row_weight = (float*)(ws + 16384 + 65536 + 2 * 131072);
  const size_t BIG = 1u << 20;
  unsigned short* xb  = (unsigned short*)(ws + BIG);         // 32 MiB
  unsigned short* w1b = xb  + (size_t)16777216;              // 32 MiB
  unsigned short* w2b = w1b + (size_t)16777216;              // 32 MiB
  unsigned short* h   = w2b + (size_t)16777216;              // 128 MiB
  const size_t REQUIRED = BIG + 3ull * 33554432ull + 134217728ull;
  if (ws_size < REQUIRED) return;

  hipMemsetAsync(d_ws, 0, 256, stream);
  cast_bf16_kernel<<<2048, 256, 0, stream>>>(w1, w1b, 16777216);
  cast_bf16_kernel<<<2048, 256, 0, stream>>>(w2, w2b, 16777216);
  routing_kernel<<<512, 256, 0, stream>>>(x, gw, logits, xb, cnt1, cnt2, tok_e01, tok_w);
  sched_kernel<<<1, 64, 0, stream>>>(cnt1, cnt2, off, sched1, sched2a, sched2b, nsched);
  scatter_kernel<<<64, 256, 0, stream>>>(tok_e01, tok_w, off, cnt1, fill0, fill1,
                                         row_token, row_weight);
  // GEMM1: h = gelu(x @ w1^T + b1)
  gemm_kernel<0, 1024, 2048><<<dim3(16, 264), 256, 0, stream>>>(
      xb, w1b, b1, h, nullptr, row_token, nullptr, sched1, nsched, 0);
  // GEMM2 pass A (slot-0 rows, store) then pass B (slot-1 rows, add)
  gemm_kernel<1, 2048, 1024><<<dim3(8, 136), 256, 0, stream>>>(
      h, w2b, b2, nullptr, out, row_token, row_weight, sched2a, nsched, 1);
  gemm_kernel<2, 2048, 1024><<<dim3(8, 136), 256, 0, stream>>>(
      h, w2b, b2, nullptr, out, row_token, row_weight, sched2b, nsched, 2);
}

// Round 4
// 743.603 us; speedup vs baseline: 1.8294x; 1.5865x over previous
//
#include <hip/hip_runtime.h>
#include <stdint.h>

#define T_TOKENS 16384
#define HID 1024
#define INTERM 2048
#define NEXP 8

typedef __bf16 bf16x8 __attribute__((ext_vector_type(8)));
typedef float f32x4 __attribute__((ext_vector_type(4)));

// ---------- helpers ----------
__device__ __forceinline__ unsigned short f2bf(float f) {
  union { float f; uint32_t u; } v; v.f = f;
  uint32_t u = v.u + 0x7fffu + ((v.u >> 16) & 1u);
  return (unsigned short)(u >> 16);
}

__device__ __forceinline__ void async16(const void* g, void* l) {
  auto gp = (const __attribute__((address_space(1))) uint32_t*)(uintptr_t)g;
  auto lp = (__attribute__((address_space(3))) uint32_t*)(uintptr_t)l;
  __builtin_amdgcn_global_load_lds(gp, lp, 16, 0, 0);
}

// tanh-form gelu via fast exp: max abs err ~3e-4 vs exact erf-gelu
__device__ __forceinline__ float gelu_fast(float v) {
  float s = 1.5957691216f * v + 0.0713548163f * v * v * v;
  return v / (1.f + __expf(-s));
}

// ---------- fp32 -> bf16 cast (weights) ----------
__global__ void cast_bf16_kernel(const float* __restrict__ in,
                                 unsigned short* __restrict__ out, int n) {
  int stride = gridDim.x * blockDim.x;
  for (int i = blockIdx.x * blockDim.x + threadIdx.x; i < (n >> 2); i += stride) {
    float4 v = reinterpret_cast<const float4*>(in)[i];
    ushort4 o;
    o.x = f2bf(v.x); o.y = f2bf(v.y); o.z = f2bf(v.z); o.w = f2bf(v.w);
    reinterpret_cast<ushort4*>(out)[i] = o;
  }
}

// ---------- routing: wave/token dot, LDS histogram (NO global atomics) ----------
// 1024 blocks x 256 thr; block handles 16 tokens (4 waves x 4 tokens).
__global__ __launch_bounds__(256, 4) void routing_kernel(
    const float* __restrict__ x, const float* __restrict__ gw,
    float* __restrict__ logits, unsigned short* __restrict__ xb,
    int* __restrict__ bh, int* __restrict__ tok_e01, float2* __restrict__ tok_w) {
  __shared__ float4 gws[2048];  // 8 experts x 1024 floats = 32 KB
  __shared__ int lh[16];        // slot0 experts [0..8), slot1 experts [8..16)
  const int tid = threadIdx.x;
  if (tid < 16) lh[tid] = 0;
  for (int i = tid; i < 2048; i += 256)
    gws[i] = reinterpret_cast<const float4*>(gw)[i];
  __syncthreads();

  const int lane = tid & 63;
  const int wave = tid >> 6;
  const int tbase = blockIdx.x * 16 + wave * 4;
#pragma unroll 2
  for (int j = 0; j < 4; ++j) {
    int t = tbase + j;
    const float4* xr = reinterpret_cast<const float4*>(x + (size_t)t * HID);
    float4 xv[4];
#pragma unroll
    for (int q = 0; q < 4; ++q) xv[q] = xr[q * 64 + lane];  // coalesced 1KB/instr
    ushort4* xbr = reinterpret_cast<ushort4*>(xb + (size_t)t * HID);
#pragma unroll
    for (int q = 0; q < 4; ++q) {
      ushort4 o;
      o.x = f2bf(xv[q].x); o.y = f2bf(xv[q].y);
      o.z = f2bf(xv[q].z); o.w = f2bf(xv[q].w);
      xbr[q * 64 + lane] = o;
    }
    float acc[NEXP];
#pragma unroll
    for (int e = 0; e < NEXP; ++e) {
      float a = 0.f;
#pragma unroll
      for (int q = 0; q < 4; ++q) {
        float4 g = gws[e * 256 + q * 64 + lane];
        a += xv[q].x * g.x + xv[q].y * g.y + xv[q].z * g.z + xv[q].w * g.w;
      }
      acc[e] = a;
    }
#pragma unroll
    for (int e = 0; e < NEXP; ++e)
#pragma unroll
      for (int off = 32; off > 0; off >>= 1)
        acc[e] += __shfl_xor(acc[e], off, 64);
    if (lane == 0) {
      int i0 = 0; float m0 = acc[0];
#pragma unroll
      for (int e = 1; e < NEXP; ++e) if (acc[e] > m0) { m0 = acc[e]; i0 = e; }
      int i1 = -1; float m1 = -3.4e38f;
#pragma unroll
      for (int e = 0; e < NEXP; ++e) if (e != i0 && acc[e] > m1) { m1 = acc[e]; i1 = e; }
      float w0 = 1.f / (1.f + expf(m1 - m0));
      float w1 = 1.f - w0;
      atomicAdd(&lh[i0], 1);       // LDS atomic — cycles, not hundreds of ns
      atomicAdd(&lh[8 + i1], 1);
      tok_e01[t] = i0 | (i1 << 16);
      tok_w[t] = make_float2(w0, w1);
      float4* lg = reinterpret_cast<float4*>(logits + (size_t)t * NEXP);
      lg[0] = make_float4(acc[0], acc[1], acc[2], acc[3]);
      lg[1] = make_float4(acc[4], acc[5], acc[6], acc[7]);
    }
  }
  __syncthreads();
  if (tid < 16) bh[blockIdx.x * 16 + tid] = lh[tid];
}

// ---------- parallel schedule: column prefix scans + tile emission ----------
// 1 block x 1024 threads (16 waves); wave c scans column c of bh[1024][16].
__global__ __launch_bounds__(1024) void sched_kernel(
    const int* __restrict__ bh, int* __restrict__ bhp, int* __restrict__ colbase,
    int4* __restrict__ sched1, int4* __restrict__ sched2a, int4* __restrict__ sched2b,
    int* __restrict__ nsched) {
  const int tid = threadIdx.x;
  const int w = tid >> 6;   // column 0..15
  const int lane = tid & 63;
  __shared__ int ct[16];
  __shared__ int offs[8];
  __shared__ int t1o[8], t2ao[8], t2bo[8];

  int carry = 0;
  for (int ch = 0; ch < 16; ++ch) {
    int b = ch * 64 + lane;
    int v = bh[b * 16 + w];
    int incl = v;
#pragma unroll
    for (int d = 1; d < 64; d <<= 1) {
      int tt = __shfl_up(incl, d, 64);
      if (lane >= d) incl += tt;
    }
    bhp[b * 16 + w] = incl - v + carry;  // exclusive prefix within column
    carry += __shfl(incl, 63, 64);
  }
  if (lane == 0) ct[w] = carry;
  __syncthreads();
  if (tid == 0) {
    int o = 0, s1 = 0, s2a = 0, s2b = 0;
    for (int e = 0; e < NEXP; ++e) {
      offs[e] = o;
      int c1 = ct[e], c2 = ct[8 + e], n = c1 + c2;
      o += n;
      t1o[e] = s1; t2ao[e] = s2a; t2bo[e] = s2b;
      s1 += (n + 127) >> 7; s2a += (c1 + 127) >> 7; s2b += (c2 + 127) >> 7;
    }
    nsched[0] = s1; nsched[1] = s2a; nsched[2] = s2b;
  }
  __syncthreads();
  if (tid < 16) colbase[tid] = offs[tid & 7] + ((tid & 8) ? ct[tid & 7] : 0);
  if (tid < 8) {
    int e = tid;
    int c1 = ct[e], c2 = ct[8 + e], n = c1 + c2, o = offs[e];
    for (int i = 0, t0 = 0; t0 < n; t0 += 128, ++i) {
      int hi = t0 + 128 < n ? t0 + 128 : n;
      sched1[t1o[e] + i] = make_int4(o + t0, o + hi, e, 0);
    }
    for (int i = 0, t0 = 0; t0 < c1; t0 += 128, ++i) {
      int hi = t0 + 128 < c1 ? t0 + 128 : c1;
      sched2a[t2ao[e] + i] = make_int4(o + t0, o + hi, e, 0);
    }
    for (int i = 0, t0 = 0; t0 < c2; t0 += 128, ++i) {
      int hi = t0 + 128 < c2 ? t0 + 128 : c2;
      sched2b[t2bo[e] + i] = make_int4(o + c1 + t0, o + c1 + hi, e, 0);
    }
  }
}

// ---------- scatter: per-block LDS ranks + precomputed bases (no global atomics) ----------
__global__ __launch_bounds__(64) void scatter_kernel(
    const int* __restrict__ tok_e01, const float2* __restrict__ tok_w,
    const int* __restrict__ bhp, const int* __restrict__ colbase,
    int* __restrict__ row_token, float* __restrict__ row_weight) {
  __shared__ int lh[16];
  const int tid = threadIdx.x;
  if (tid < 16) lh[tid] = 0;
  __syncthreads();
  if (tid < 16) {
    int t = blockIdx.x * 16 + tid;
    int p = tok_e01[t];
    int e0 = p & 0xffff, e1 = p >> 16;
    float2 w = tok_w[t];
    int r0 = atomicAdd(&lh[e0], 1);
    int pos0 = colbase[e0] + bhp[blockIdx.x * 16 + e0] + r0;
    row_token[pos0] = t; row_weight[pos0] = w.x;
    int r1 = atomicAdd(&lh[8 + e1], 1);
    int pos1 = colbase[8 + e1] + bhp[blockIdx.x * 16 + 8 + e1] + r1;
    row_token[pos1] = t; row_weight[pos1] = w.y;
  }
}

// ---------- grouped GEMM, 128x128xBK64, 4 waves, 2-phase double-buffered ----------
template <int MODE, int KDIM, int NDIM>
__global__ __launch_bounds__(256) void gemm_kernel(
    const unsigned short* __restrict__ A, const unsigned short* __restrict__ Bw,
    const float* __restrict__ bias, unsigned short* __restrict__ hOut,
    float* __restrict__ out, const int* __restrict__ row_token,
    const float* __restrict__ row_weight, const int4* __restrict__ sched,
    const int* __restrict__ nsched_p, int nsched_idx) {
  const int sid = blockIdx.y;  // col-blocks launch-adjacent -> A-tile L2 reuse
  if (sid >= nsched_p[nsched_idx]) return;
  int4 s = sched[sid];
  const int row_start = s.x, row_limit = s.y, e = s.z;
  const int colBase = blockIdx.x * 128;

  __shared__ __attribute__((aligned(16))) unsigned short As[2][128 * 64];
  __shared__ __attribute__((aligned(16))) unsigned short Bs[2][128 * 64];

  const int tid = threadIdx.x;
  const int wave = tid >> 6;
  const int lane = tid & 63;

  const unsigned short* aSrc[4];
  const unsigned short* bSrc[4];
  const unsigned short* Bbase = Bw + (size_t)e * (2048 * 1024);
  const int kkel = (tid & 7) * 8;
#pragma unroll
  for (int i = 0; i < 4; ++i) {
    int r = (i * 256 + tid) >> 3;
    int rg = row_start + r;
    rg = rg < row_limit ? rg : (row_limit - 1);
    if (MODE == 0) {
      int tok = row_token[rg];
      aSrc[i] = A + (size_t)tok * KDIM + kkel;
    } else {
      aSrc[i] = A + (size_t)rg * KDIM + kkel;
    }
    bSrc[i] = Bbase + (size_t)(colBase + r) * KDIM + kkel;
  }

  f32x4 zero = {0.f, 0.f, 0.f, 0.f};
  f32x4 acc[4][4];
#pragma unroll
  for (int m = 0; m < 4; ++m)
#pragma unroll
    for (int n = 0; n < 4; ++n) acc[m][n] = zero;

  const int aRow = (wave >> 1) * 64 + (lane & 15);
  const int bRow = (wave & 1) * 64 + (lane & 15);
  const int kB = (lane >> 4) * 16;
  const int NT = KDIM / 64;

  auto stage = [&](int buf, int kt) {
    const size_t koff = (size_t)kt * 128;
    char* AsB = (char*)As[buf];
    char* BsB = (char*)Bs[buf];
#pragma unroll
    for (int i = 0; i < 4; ++i) {
      async16((const char*)aSrc[i] + koff, AsB + (i * 4 + wave) * 1024);
      async16((const char*)bSrc[i] + koff, BsB + (i * 4 + wave) * 1024);
    }
  };
  auto compute = [&](int buf) {
    const char* AsB = (const char*)As[buf];
    const char* BsB = (const char*)Bs[buf];
#pragma unroll
    for (int ks = 0; ks < 2; ++ks) {
      bf16x8 af[4], bfr[4];
#pragma unroll
      for (int m = 0; m < 4; ++m)
        af[m] = *reinterpret_cast<const bf16x8*>(AsB + (aRow + m * 16) * 128 + ks * 64 + kB);
#pragma unroll
      for (int n = 0; n < 4; ++n)
        bfr[n] = *reinterpret_cast<const bf16x8*>(BsB + (bRow + n * 16) * 128 + ks * 64 + kB);
#pragma unroll
      for (int m = 0; m < 4; ++m)
#pragma unroll
        for (int n = 0; n < 4; ++n)
          acc[m][n] = __builtin_amdgcn_mfma_f32_16x16x32_bf16(af[m], bfr[n], acc[m][n], 0, 0, 0);
    }
  };

  stage(0, 0);
  __syncthreads();
  int cur = 0;
  for (int kt = 0; kt < NT - 1; ++kt) {
    stage(cur ^ 1, kt + 1);
    compute(cur);
    __syncthreads();
    cur ^= 1;
  }
  compute(cur);

  const int cCol = lane & 15;
  const int cRowB = (lane >> 4) * 4;
  const int wrBase = (wave >> 1) * 64;
  const int wcBase = (wave & 1) * 64;

  if (MODE == 0) {
#pragma unroll
    for (int n = 0; n < 4; ++n) {
      int col = colBase + wcBase + n * 16 + cCol;
      float bb = bias[e * NDIM + col];
#pragma unroll
      for (int m = 0; m < 4; ++m) {
#pragma unroll
        for (int j = 0; j < 4; ++j) {
          int r = row_start + wrBase + m * 16 + cRowB + j;
          if (r < row_limit) {
            float v = gelu_fast(acc[m][n][j] + bb);
            hOut[(size_t)r * NDIM + col] = f2bf(v);
          }
        }
      }
    }
  } else {
#pragma unroll
    for (int m = 0; m < 4; ++m) {
#pragma unroll
      for (int j = 0; j < 4; ++j) {
        int rr = row_start + wrBase + m * 16 + cRowB + j;
        if (rr < row_limit) {
          int tok = row_token[rr];
          float wgt = row_weight[rr];
          float* orow = out + (size_t)tok * NDIM;
#pragma unroll
          for (int n = 0; n < 4; ++n) {
            int col = colBase + wcBase + n * 16 + cCol;
            float v = wgt * (acc[m][n][j] + bias[e * NDIM + col]);
            if (MODE == 2) v += orow[col];  // pass A completed (stream order)
            orow[col] = v;
          }
        }
      }
    }
  }
}

// ---------- launch ----------
extern "C" void kernel_launch(void* const* d_in, const int* in_sizes, int n_in,
                              void* d_out, int out_size, void* d_ws, size_t ws_size,
                              hipStream_t stream) {
  const float* x  = (const float*)d_in[0];
  const float* gw = (const float*)d_in[1];
  const float* w1 = (const float*)d_in[2];
  const float* b1 = (const float*)d_in[3];
  const float* w2 = (const float*)d_in[4];
  const float* b2 = (const float*)d_in[5];
  float* out = (float*)d_out;
  float* logits = out + (size_t)T_TOKENS * HID;

  char* ws = (char*)d_ws;
  int* nsched = (int*)ws;            // 3 ints
  int* colbase = (int*)(ws + 64);    // 16 ints
  int4* sched1  = (int4*)(ws + 512);               // <=264 entries
  int4* sched2a = (int4*)(ws + 512 + 4352);        // <=136
  int4* sched2b = (int4*)(ws + 512 + 4352 + 2304); // <=136
  int* tok_e01 = (int*)(ws + 16384);                              // 64 KB
  float2* tok_w = (float2*)(ws + 16384 + 65536);                  // 128 KB
  int* row_token = (int*)(ws + 16384 + 65536 + 131072);           // 128 KB
  float* row_weight = (float*)(ws + 16384 + 65536 + 2 * 131072);  // 128 KB
  int* bh  = (int*)(ws + 16384 + 65536 + 3 * 131072);             // 64 KB [1024][16]
  int* bhp = bh + 16384;                                          // 64 KB
  const size_t BIG = 1u << 20;
  unsigned short* xb  = (unsigned short*)(ws + BIG);  // 32 MiB
  unsigned short* w1b = xb  + (size_t)16777216;       // 32 MiB
  unsigned short* w2b = w1b + (size_t)16777216;       // 32 MiB
  unsigned short* h   = w2b + (size_t)16777216;       // 128 MiB
  const size_t REQUIRED = BIG + 3ull * 33554432ull + 134217728ull;
  if (ws_size < REQUIRED) return;

  cast_bf16_kernel<<<2048, 256, 0, stream>>>(w1, w1b, 16777216);
  cast_bf16_kernel<<<2048, 256, 0, stream>>>(w2, w2b, 16777216);
  routing_kernel<<<1024, 256, 0, stream>>>(x, gw, logits, xb, bh, tok_e01, tok_w);
  sched_kernel<<<1, 1024, 0, stream>>>(bh, bhp, colbase, sched1, sched2a, sched2b, nsched);
  scatter_kernel<<<1024, 64, 0, stream>>>(tok_e01, tok_w, bhp, colbase,
                                          row_token, row_weight);
  // GEMM1: h = gelu(x @ w1^T + b1)
  gemm_kernel<0, 1024, 2048><<<dim3(16, 264), 256, 0, stream>>>(
      xb, w1b, b1, h, nullptr, row_token, nullptr, sched1, nsched, 0);
  // GEMM2 pass A (slot-0 rows, store) then pass B (slot-1 rows, add)
  gemm_kernel<1, 2048, 1024><<<dim3(8, 136), 256, 0, stream>>>(
      h, w2b, b2, nullptr, out, row_token, row_weight, sched2a, nsched, 1);
  gemm_kernel<2, 2048, 1024><<<dim3(8, 136), 256, 0, stream>>>(
      h, w2b, b2, nullptr, out, row_token, row_weight, sched2b, nsched, 2);
}

// Round 5
// 742.725 us; speedup vs baseline: 1.8316x; 1.0012x over previous
//
#include <hip/hip_runtime.h>
#include <stdint.h>

#define T_TOKENS 16384
#define HID 1024
#define INTERM 2048
#define NEXP 8

typedef __bf16 bf16x8 __attribute__((ext_vector_type(8)));
typedef float f32x4 __attribute__((ext_vector_type(4)));

// ---------- helpers ----------
__device__ __forceinline__ unsigned short f2bf(float f) {
  union { float f; uint32_t u; } v; v.f = f;
  uint32_t u = v.u + 0x7fffu + ((v.u >> 16) & 1u);
  return (unsigned short)(u >> 16);
}

__device__ __forceinline__ void async16(const void* g, void* l) {
  auto gp = (const __attribute__((address_space(1))) uint32_t*)(uintptr_t)g;
  auto lp = (__attribute__((address_space(3))) uint32_t*)(uintptr_t)l;
  __builtin_amdgcn_global_load_lds(gp, lp, 16, 0, 0);
}

// tanh-form gelu via fast exp: max abs err ~3e-4 vs exact erf-gelu
__device__ __forceinline__ float gelu_fast(float v) {
  float s = 1.5957691216f * v + 0.0713548163f * v * v * v;
  return v / (1.f + __expf(-s));
}

// ---------- fp32 -> bf16 cast (weights) ----------
__global__ void cast_bf16_kernel(const float* __restrict__ in,
                                 unsigned short* __restrict__ out, int n) {
  int stride = gridDim.x * blockDim.x;
  for (int i = blockIdx.x * blockDim.x + threadIdx.x; i < (n >> 2); i += stride) {
    float4 v = reinterpret_cast<const float4*>(in)[i];
    ushort4 o;
    o.x = f2bf(v.x); o.y = f2bf(v.y); o.z = f2bf(v.z); o.w = f2bf(v.w);
    reinterpret_cast<ushort4*>(out)[i] = o;
  }
}

// ---------- routing: wave/token dot, LDS histogram (NO global atomics) ----------
__global__ __launch_bounds__(256, 4) void routing_kernel(
    const float* __restrict__ x, const float* __restrict__ gw,
    float* __restrict__ logits, unsigned short* __restrict__ xb,
    int* __restrict__ bh, int* __restrict__ tok_e01, float2* __restrict__ tok_w) {
  __shared__ float4 gws[2048];  // 8 experts x 1024 floats = 32 KB
  __shared__ int lh[16];
  const int tid = threadIdx.x;
  if (tid < 16) lh[tid] = 0;
  for (int i = tid; i < 2048; i += 256)
    gws[i] = reinterpret_cast<const float4*>(gw)[i];
  __syncthreads();

  const int lane = tid & 63;
  const int wave = tid >> 6;
  const int tbase = blockIdx.x * 16 + wave * 4;
#pragma unroll 2
  for (int j = 0; j < 4; ++j) {
    int t = tbase + j;
    const float4* xr = reinterpret_cast<const float4*>(x + (size_t)t * HID);
    float4 xv[4];
#pragma unroll
    for (int q = 0; q < 4; ++q) xv[q] = xr[q * 64 + lane];
    ushort4* xbr = reinterpret_cast<ushort4*>(xb + (size_t)t * HID);
#pragma unroll
    for (int q = 0; q < 4; ++q) {
      ushort4 o;
      o.x = f2bf(xv[q].x); o.y = f2bf(xv[q].y);
      o.z = f2bf(xv[q].z); o.w = f2bf(xv[q].w);
      xbr[q * 64 + lane] = o;
    }
    float acc[NEXP];
#pragma unroll
    for (int e = 0; e < NEXP; ++e) {
      float a = 0.f;
#pragma unroll
      for (int q = 0; q < 4; ++q) {
        float4 g = gws[e * 256 + q * 64 + lane];
        a += xv[q].x * g.x + xv[q].y * g.y + xv[q].z * g.z + xv[q].w * g.w;
      }
      acc[e] = a;
    }
#pragma unroll
    for (int e = 0; e < NEXP; ++e)
#pragma unroll
      for (int off = 32; off > 0; off >>= 1)
        acc[e] += __shfl_xor(acc[e], off, 64);
    if (lane == 0) {
      int i0 = 0; float m0 = acc[0];
#pragma unroll
      for (int e = 1; e < NEXP; ++e) if (acc[e] > m0) { m0 = acc[e]; i0 = e; }
      int i1 = -1; float m1 = -3.4e38f;
#pragma unroll
      for (int e = 0; e < NEXP; ++e) if (e != i0 && acc[e] > m1) { m1 = acc[e]; i1 = e; }
      float w0 = 1.f / (1.f + expf(m1 - m0));
      float w1 = 1.f - w0;
      atomicAdd(&lh[i0], 1);
      atomicAdd(&lh[8 + i1], 1);
      tok_e01[t] = i0 | (i1 << 16);
      tok_w[t] = make_float2(w0, w1);
      float4* lg = reinterpret_cast<float4*>(logits + (size_t)t * NEXP);
      lg[0] = make_float4(acc[0], acc[1], acc[2], acc[3]);
      lg[1] = make_float4(acc[4], acc[5], acc[6], acc[7]);
    }
  }
  __syncthreads();
  if (tid < 16) bh[blockIdx.x * 16 + tid] = lh[tid];
}

// ---------- parallel schedule: column prefix scans + 256-row tile emission ----------
__global__ __launch_bounds__(1024) void sched_kernel(
    const int* __restrict__ bh, int* __restrict__ bhp, int* __restrict__ colbase,
    int4* __restrict__ sched1, int4* __restrict__ sched2a, int4* __restrict__ sched2b,
    int* __restrict__ nsched) {
  const int tid = threadIdx.x;
  const int w = tid >> 6;
  const int lane = tid & 63;
  __shared__ int ct[16];
  __shared__ int offs[8];
  __shared__ int t1o[8], t2ao[8], t2bo[8];

  int carry = 0;
  for (int ch = 0; ch < 16; ++ch) {
    int b = ch * 64 + lane;
    int v = bh[b * 16 + w];
    int incl = v;
#pragma unroll
    for (int d = 1; d < 64; d <<= 1) {
      int tt = __shfl_up(incl, d, 64);
      if (lane >= d) incl += tt;
    }
    bhp[b * 16 + w] = incl - v + carry;
    carry += __shfl(incl, 63, 64);
  }
  if (lane == 0) ct[w] = carry;
  __syncthreads();
  if (tid == 0) {
    int o = 0, s1 = 0, s2a = 0, s2b = 0;
    for (int e = 0; e < NEXP; ++e) {
      offs[e] = o;
      int c1 = ct[e], c2 = ct[8 + e], n = c1 + c2;
      o += n;
      t1o[e] = s1; t2ao[e] = s2a; t2bo[e] = s2b;
      s1 += (n + 255) >> 8; s2a += (c1 + 255) >> 8; s2b += (c2 + 255) >> 8;
    }
    nsched[0] = s1; nsched[1] = s2a; nsched[2] = s2b;
  }
  __syncthreads();
  if (tid < 16) colbase[tid] = offs[tid & 7] + ((tid & 8) ? ct[tid & 7] : 0);
  if (tid < 8) {
    int e = tid;
    int c1 = ct[e], c2 = ct[8 + e], n = c1 + c2, o = offs[e];
    for (int i = 0, t0 = 0; t0 < n; t0 += 256, ++i) {
      int hi = t0 + 256 < n ? t0 + 256 : n;
      sched1[t1o[e] + i] = make_int4(o + t0, o + hi, e, 0);
    }
    for (int i = 0, t0 = 0; t0 < c1; t0 += 256, ++i) {
      int hi = t0 + 256 < c1 ? t0 + 256 : c1;
      sched2a[t2ao[e] + i] = make_int4(o + t0, o + hi, e, 0);
    }
    for (int i = 0, t0 = 0; t0 < c2; t0 += 256, ++i) {
      int hi = t0 + 256 < c2 ? t0 + 256 : c2;
      sched2b[t2bo[e] + i] = make_int4(o + c1 + t0, o + c1 + hi, e, 0);
    }
  }
}

// ---------- scatter: per-block LDS ranks + precomputed bases ----------
__global__ __launch_bounds__(64) void scatter_kernel(
    const int* __restrict__ tok_e01, const float2* __restrict__ tok_w,
    const int* __restrict__ bhp, const int* __restrict__ colbase,
    int* __restrict__ row_token, float* __restrict__ row_weight) {
  __shared__ int lh[16];
  const int tid = threadIdx.x;
  if (tid < 16) lh[tid] = 0;
  __syncthreads();
  if (tid < 16) {
    int t = blockIdx.x * 16 + tid;
    int p = tok_e01[t];
    int e0 = p & 0xffff, e1 = p >> 16;
    float2 w = tok_w[t];
    int r0 = atomicAdd(&lh[e0], 1);
    int pos0 = colbase[e0] + bhp[blockIdx.x * 16 + e0] + r0;
    row_token[pos0] = t; row_weight[pos0] = w.x;
    int r1 = atomicAdd(&lh[8 + e1], 1);
    int pos1 = colbase[8 + e1] + bhp[blockIdx.x * 16 + 8 + e1] + r1;
    row_token[pos1] = t; row_weight[pos1] = w.y;
  }
}

// ---------- grouped GEMM 256x256xBK64, 8 waves, counted-vmcnt pipeline ----------
// T2: chunk ^= (row&7) swizzle (linear gload_lds dest + inverse-swz global src)
// T4: vmcnt(8) steady-state (never 0 mid-loop). T5: setprio around MFMA cluster.
// MODE 0: A gathered via row_token, epilogue gelu(.+b1) -> h (bf16)
// MODE 1: A = h rows, out[tok]  = w*(acc+b2)
// MODE 2: A = h rows, out[tok] += w*(acc+b2)
template <int MODE, int KDIM, int NDIM, int NSMAX>
__global__ __launch_bounds__(512, 2) void gemm256_kernel(
    const unsigned short* __restrict__ A, const unsigned short* __restrict__ Bw,
    const float* __restrict__ bias, unsigned short* __restrict__ hOut,
    float* __restrict__ out, const int* __restrict__ row_token,
    const float* __restrict__ row_weight, const int4* __restrict__ sched,
    const int* __restrict__ nsched_p, int nsched_idx) {
  constexpr int NCOL = NDIM / 256;
  constexpr int CHUNK = NSMAX * NCOL / 8;  // NWG multiple of 8 by construction
  // T1: XCD gets contiguous logical chunk; logical L = sid*NCOL + colblk
  const int flat = blockIdx.x;
  const int L = (flat & 7) * CHUNK + (flat >> 3);
  const int sid = L / NCOL;
  const int colblk = L - sid * NCOL;
  if (sid >= nsched_p[nsched_idx]) return;
  int4 s = sched[sid];
  const int row_start = s.x, row_limit = s.y, e = s.z;
  const int colBase = colblk * 256;

  __shared__ __attribute__((aligned(16))) unsigned short As[2][256 * 64];
  __shared__ __attribute__((aligned(16))) unsigned short Bs[2][256 * 64];

  const int tid = threadIdx.x;
  const int w = tid >> 6;
  const int lane = tid & 63;
  const int wr = w >> 2;   // 0..1  (M half)
  const int wc = w & 3;    // 0..3  (N quarter)

  // --- staging geometry: thread covers (row = i*64 + w*8 + (lane>>3), phys chunk lane&7)
  // T2 write side: fetch logical chunk (phys ^ row&7); row&7 == lane>>3 here.
  const int srow = w * 8 + (lane >> 3);
  const int schunk = (lane & 7) ^ (lane >> 3);
  const unsigned short* aG[4];
  const unsigned short* bG[4];
  const unsigned short* Bbase = Bw + (size_t)e * ((size_t)NDIM * KDIM);
#pragma unroll
  for (int i = 0; i < 4; ++i) {
    int r = i * 64 + srow;
    int rg = row_start + r;
    rg = rg < row_limit ? rg : (row_limit - 1);
    int arow = (MODE == 0) ? row_token[rg] : rg;
    aG[i] = A + (size_t)arow * KDIM + schunk * 8;
    bG[i] = Bbase + (size_t)(colBase + r) * KDIM + schunk * 8;
  }

  f32x4 zero = {0.f, 0.f, 0.f, 0.f};
  f32x4 acc[8][4];
#pragma unroll
  for (int m = 0; m < 8; ++m)
#pragma unroll
    for (int n = 0; n < 4; ++n) acc[m][n] = zero;

  auto stage = [&](int buf, int kt) {
    const size_t koff = (size_t)kt * 64;  // elements
    char* Ad = ((char*)As) + buf * 32768;
    char* Bd = ((char*)Bs) + buf * 32768;
#pragma unroll
    for (int i = 0; i < 4; ++i) {
      async16(aG[i] + koff, Ad + (i * 8 + w) * 1024);  // HW adds lane*16
      async16(bG[i] + koff, Bd + (i * 8 + w) * 1024);
    }
  };

  const int rl = lane & 15;        // frag row-within-16
  const int ch0 = lane >> 4;       // frag chunk base 0..3
  const int swz = rl & 7;          // row&7 for all frag rows (bases are x16)
  auto compute = [&](int buf) {
    const char* Ab = ((const char*)As) + buf * 32768;
    const char* Bb = ((const char*)Bs) + buf * 32768;
#pragma unroll
    for (int ks = 0; ks < 2; ++ks) {
      const int ccl = ((ks * 4 + ch0) ^ swz) * 16;  // swizzled chunk byte offset
      bf16x8 bfr[4];
#pragma unroll
      for (int n = 0; n < 4; ++n) {
        int r = wc * 64 + n * 16 + rl;
        bfr[n] = *reinterpret_cast<const bf16x8*>(Bb + r * 128 + ccl);
      }
      __builtin_amdgcn_s_setprio(1);
#pragma unroll
      for (int m = 0; m < 8; ++m) {
        int r = wr * 128 + m * 16 + rl;
        bf16x8 afm = *reinterpret_cast<const bf16x8*>(Ab + r * 128 + ccl);
#pragma unroll
        for (int n = 0; n < 4; ++n)
          acc[m][n] = __builtin_amdgcn_mfma_f32_16x16x32_bf16(afm, bfr[n], acc[m][n], 0, 0, 0);
      }
      __builtin_amdgcn_s_setprio(0);
    }
  };

  const int NT = KDIM / 64;
  stage(0, 0);
  stage(1, 1);
  for (int kt = 0; kt < NT; ++kt) {
    if (kt < NT - 1) {
      asm volatile("s_waitcnt vmcnt(8)" ::: "memory");  // this K-tile landed; next still flying
    } else {
      asm volatile("s_waitcnt vmcnt(0)" ::: "memory");  // final drain
    }
    __builtin_amdgcn_s_barrier();
    asm volatile("" ::: "memory");
    compute(kt & 1);
    if (kt + 2 < NT) {
      asm volatile("" ::: "memory");
      __builtin_amdgcn_s_barrier();  // all waves done reading this buffer
      stage(kt & 1, kt + 2);
    }
  }

  // epilogue: C/D map col=lane&15, row=(lane>>4)*4+j
  const int cCol = lane & 15;
  const int cRowB = (lane >> 4) * 4;

  if (MODE == 0) {
#pragma unroll
    for (int n = 0; n < 4; ++n) {
      int col = colBase + wc * 64 + n * 16 + cCol;
      float bb = bias[e * NDIM + col];
#pragma unroll
      for (int m = 0; m < 8; ++m) {
#pragma unroll
        for (int j = 0; j < 4; ++j) {
          int r = row_start + wr * 128 + m * 16 + cRowB + j;
          if (r < row_limit) {
            float v = gelu_fast(acc[m][n][j] + bb);
            hOut[(size_t)r * NDIM + col] = f2bf(v);
          }
        }
      }
    }
  } else {
#pragma unroll
    for (int m = 0; m < 8; ++m) {
#pragma unroll
      for (int j = 0; j < 4; ++j) {
        int rr = row_start + wr * 128 + m * 16 + cRowB + j;
        if (rr < row_limit) {
          int tok = row_token[rr];
          float wgt = row_weight[rr];
          float* orow = out + (size_t)tok * NDIM;
#pragma unroll
          for (int n = 0; n < 4; ++n) {
            int col = colBase + wc * 64 + n * 16 + cCol;
            float v = wgt * (acc[m][n][j] + bias[e * NDIM + col]);
            if (MODE == 2) v += orow[col];  // pass A completed (stream order)
            orow[col] = v;
          }
        }
      }
    }
  }
}

// ---------- launch ----------
extern "C" void kernel_launch(void* const* d_in, const int* in_sizes, int n_in,
                              void* d_out, int out_size, void* d_ws, size_t ws_size,
                              hipStream_t stream) {
  const float* x  = (const float*)d_in[0];
  const float* gw = (const float*)d_in[1];
  const float* w1 = (const float*)d_in[2];
  const float* b1 = (const float*)d_in[3];
  const float* w2 = (const float*)d_in[4];
  const float* b2 = (const float*)d_in[5];
  float* out = (float*)d_out;
  float* logits = out + (size_t)T_TOKENS * HID;

  char* ws = (char*)d_ws;
  int* nsched = (int*)ws;
  int* colbase = (int*)(ws + 64);
  int4* sched1  = (int4*)(ws + 512);
  int4* sched2a = (int4*)(ws + 512 + 4352);
  int4* sched2b = (int4*)(ws + 512 + 4352 + 2304);
  int* tok_e01 = (int*)(ws + 16384);
  float2* tok_w = (float2*)(ws + 16384 + 65536);
  int* row_token = (int*)(ws + 16384 + 65536 + 131072);
  float* row_weight = (float*)(ws + 16384 + 65536 + 2 * 131072);
  int* bh  = (int*)(ws + 16384 + 65536 + 3 * 131072);
  int* bhp = bh + 16384;
  const size_t BIG = 1u << 20;
  unsigned short* xb  = (unsigned short*)(ws + BIG);  // 32 MiB
  unsigned short* w1b = xb  + (size_t)16777216;       // 32 MiB
  unsigned short* w2b = w1b + (size_t)16777216;       // 32 MiB
  unsigned short* h   = w2b + (size_t)16777216;       // 128 MiB
  const size_t REQUIRED = BIG + 3ull * 33554432ull + 134217728ull;
  if (ws_size < REQUIRED) return;

  cast_bf16_kernel<<<2048, 256, 0, stream>>>(w1, w1b, 16777216);
  cast_bf16_kernel<<<2048, 256, 0, stream>>>(w2, w2b, 16777216);
  routing_kernel<<<1024, 256, 0, stream>>>(x, gw, logits, xb, bh, tok_e01, tok_w);
  sched_kernel<<<1, 1024, 0, stream>>>(bh, bhp, colbase, sched1, sched2a, sched2b, nsched);
  scatter_kernel<<<1024, 64, 0, stream>>>(tok_e01, tok_w, bhp, colbase,
                                          row_token, row_weight);
  // GEMM1: h = gelu(x @ w1^T + b1); NSMAX=136 -> grid 1088 (%8==0 for T1 remap)
  gemm256_kernel<0, 1024, 2048, 136><<<1088, 512, 0, stream>>>(
      xb, w1b, b1, h, nullptr, row_token, nullptr, sched1, nsched, 0);
  // GEMM2 pass A (slot-0 rows, store) then pass B (slot-1 rows, add); NSMAX=72 -> 288
  gemm256_kernel<1, 2048, 1024, 72><<<288, 512, 0, stream>>>(
      h, w2b, b2, nullptr, out, row_token, row_weight, sched2a, nsched, 1);
  gemm256_kernel<2, 2048, 1024, 72><<<288, 512, 0, stream>>>(
      h, w2b, b2, nullptr, out, row_token, row_weight, sched2b, nsched, 2);
}

// Round 7
// 706.932 us; speedup vs baseline: 1.9243x; 1.0506x over previous
//
#include <hip/hip_runtime.h>
#include <stdint.h>

#define T_TOKENS 16384
#define HID 1024
#define INTERM 2048
#define NEXP 8

typedef __bf16 bf16x8 __attribute__((ext_vector_type(8)));
typedef float f32x4 __attribute__((ext_vector_type(4)));

// ---------- helpers ----------
__device__ __forceinline__ unsigned short f2bf(float f) {
  union { float f; uint32_t u; } v; v.f = f;
  uint32_t u = v.u + 0x7fffu + ((v.u >> 16) & 1u);
  return (unsigned short)(u >> 16);
}

__device__ __forceinline__ void async16(const void* g, void* l) {
  auto gp = (const __attribute__((address_space(1))) uint32_t*)(uintptr_t)g;
  auto lp = (__attribute__((address_space(3))) uint32_t*)(uintptr_t)l;
  __builtin_amdgcn_global_load_lds(gp, lp, 16, 0, 0);
}

// tanh-form gelu via fast exp: max abs err ~3e-4 vs exact erf-gelu
__device__ __forceinline__ float gelu_fast(float v) {
  float s = 1.5957691216f * v + 0.0713548163f * v * v * v;
  return v / (1.f + __expf(-s));
}

// ---------- fp32 -> bf16 cast (weights) ----------
__global__ void cast_bf16_kernel(const float* __restrict__ in,
                                 unsigned short* __restrict__ out, int n) {
  int stride = gridDim.x * blockDim.x;
  for (int i = blockIdx.x * blockDim.x + threadIdx.x; i < (n >> 2); i += stride) {
    float4 v = reinterpret_cast<const float4*>(in)[i];
    ushort4 o;
    o.x = f2bf(v.x); o.y = f2bf(v.y); o.z = f2bf(v.z); o.w = f2bf(v.w);
    reinterpret_cast<ushort4*>(out)[i] = o;
  }
}

// ---------- routing: wave/token dot, LDS histogram (NO global atomics) ----------
__global__ __launch_bounds__(256, 4) void routing_kernel(
    const float* __restrict__ x, const float* __restrict__ gw,
    float* __restrict__ logits, unsigned short* __restrict__ xb,
    int* __restrict__ bh, int* __restrict__ tok_e01, float2* __restrict__ tok_w) {
  __shared__ float4 gws[2048];  // 8 experts x 1024 floats = 32 KB
  __shared__ int lh[16];
  const int tid = threadIdx.x;
  if (tid < 16) lh[tid] = 0;
  for (int i = tid; i < 2048; i += 256)
    gws[i] = reinterpret_cast<const float4*>(gw)[i];
  __syncthreads();

  const int lane = tid & 63;
  const int wave = tid >> 6;
  const int tbase = blockIdx.x * 16 + wave * 4;
#pragma unroll 2
  for (int j = 0; j < 4; ++j) {
    int t = tbase + j;
    const float4* xr = reinterpret_cast<const float4*>(x + (size_t)t * HID);
    float4 xv[4];
#pragma unroll
    for (int q = 0; q < 4; ++q) xv[q] = xr[q * 64 + lane];
    ushort4* xbr = reinterpret_cast<ushort4*>(xb + (size_t)t * HID);
#pragma unroll
    for (int q = 0; q < 4; ++q) {
      ushort4 o;
      o.x = f2bf(xv[q].x); o.y = f2bf(xv[q].y);
      o.z = f2bf(xv[q].z); o.w = f2bf(xv[q].w);
      xbr[q * 64 + lane] = o;
    }
    float acc[NEXP];
#pragma unroll
    for (int e = 0; e < NEXP; ++e) {
      float a = 0.f;
#pragma unroll
      for (int q = 0; q < 4; ++q) {
        float4 g = gws[e * 256 + q * 64 + lane];
        a += xv[q].x * g.x + xv[q].y * g.y + xv[q].z * g.z + xv[q].w * g.w;
      }
      acc[e] = a;
    }
#pragma unroll
    for (int e = 0; e < NEXP; ++e)
#pragma unroll
      for (int off = 32; off > 0; off >>= 1)
        acc[e] += __shfl_xor(acc[e], off, 64);
    if (lane == 0) {
      int i0 = 0; float m0 = acc[0];
#pragma unroll
      for (int e = 1; e < NEXP; ++e) if (acc[e] > m0) { m0 = acc[e]; i0 = e; }
      int i1 = -1; float m1 = -3.4e38f;
#pragma unroll
      for (int e = 0; e < NEXP; ++e) if (e != i0 && acc[e] > m1) { m1 = acc[e]; i1 = e; }
      float w0 = 1.f / (1.f + expf(m1 - m0));
      float w1 = 1.f - w0;
      atomicAdd(&lh[i0], 1);
      atomicAdd(&lh[8 + i1], 1);
      tok_e01[t] = i0 | (i1 << 16);
      tok_w[t] = make_float2(w0, w1);
      float4* lg = reinterpret_cast<float4*>(logits + (size_t)t * NEXP);
      lg[0] = make_float4(acc[0], acc[1], acc[2], acc[3]);
      lg[1] = make_float4(acc[4], acc[5], acc[6], acc[7]);
    }
  }
  __syncthreads();
  if (tid < 16) bh[blockIdx.x * 16 + tid] = lh[tid];
}

// ---------- parallel schedule: column prefix scans + 256-row tile emission ----------
__global__ __launch_bounds__(1024) void sched_kernel(
    const int* __restrict__ bh, int* __restrict__ bhp, int* __restrict__ colbase,
    int4* __restrict__ sched1, int4* __restrict__ sched2a, int4* __restrict__ sched2b,
    int* __restrict__ nsched) {
  const int tid = threadIdx.x;
  const int w = tid >> 6;
  const int lane = tid & 63;
  __shared__ int ct[16];
  __shared__ int offs[8];
  __shared__ int t1o[8], t2ao[8], t2bo[8];

  int carry = 0;
  for (int ch = 0; ch < 16; ++ch) {
    int b = ch * 64 + lane;
    int v = bh[b * 16 + w];
    int incl = v;
#pragma unroll
    for (int d = 1; d < 64; d <<= 1) {
      int tt = __shfl_up(incl, d, 64);
      if (lane >= d) incl += tt;
    }
    bhp[b * 16 + w] = incl - v + carry;
    carry += __shfl(incl, 63, 64);
  }
  if (lane == 0) ct[w] = carry;
  __syncthreads();
  if (tid == 0) {
    int o = 0, s1 = 0, s2a = 0, s2b = 0;
    for (int e = 0; e < NEXP; ++e) {
      offs[e] = o;
      int c1 = ct[e], c2 = ct[8 + e], n = c1 + c2;
      o += n;
      t1o[e] = s1; t2ao[e] = s2a; t2bo[e] = s2b;
      s1 += (n + 255) >> 8; s2a += (c1 + 255) >> 8; s2b += (c2 + 255) >> 8;
    }
    nsched[0] = s1; nsched[1] = s2a; nsched[2] = s2b;
  }
  __syncthreads();
  if (tid < 16) colbase[tid] = offs[tid & 7] + ((tid & 8) ? ct[tid & 7] : 0);
  if (tid < 8) {
    int e = tid;
    int c1 = ct[e], c2 = ct[8 + e], n = c1 + c2, o = offs[e];
    for (int i = 0, t0 = 0; t0 < n; t0 += 256, ++i) {
      int hi = t0 + 256 < n ? t0 + 256 : n;
      sched1[t1o[e] + i] = make_int4(o + t0, o + hi, e, 0);
    }
    for (int i = 0, t0 = 0; t0 < c1; t0 += 256, ++i) {
      int hi = t0 + 256 < c1 ? t0 + 256 : c1;
      sched2a[t2ao[e] + i] = make_int4(o + t0, o + hi, e, 0);
    }
    for (int i = 0, t0 = 0; t0 < c2; t0 += 256, ++i) {
      int hi = t0 + 256 < c2 ? t0 + 256 : c2;
      sched2b[t2bo[e] + i] = make_int4(o + c1 + t0, o + c1 + hi, e, 0);
    }
  }
}

// ---------- scatter: per-block LDS ranks + precomputed bases ----------
__global__ __launch_bounds__(64) void scatter_kernel(
    const int* __restrict__ tok_e01, const float2* __restrict__ tok_w,
    const int* __restrict__ bhp, const int* __restrict__ colbase,
    int* __restrict__ row_token, float* __restrict__ row_weight) {
  __shared__ int lh[16];
  const int tid = threadIdx.x;
  if (tid < 16) lh[tid] = 0;
  __syncthreads();
  if (tid < 16) {
    int t = blockIdx.x * 16 + tid;
    int p = tok_e01[t];
    int e0 = p & 0xffff, e1 = p >> 16;
    float2 w = tok_w[t];
    int r0 = atomicAdd(&lh[e0], 1);
    int pos0 = colbase[e0] + bhp[blockIdx.x * 16 + e0] + r0;
    row_token[pos0] = t; row_weight[pos0] = w.x;
    int r1 = atomicAdd(&lh[8 + e1], 1);
    int pos1 = colbase[8 + e1] + bhp[blockIdx.x * 16 + 8 + e1] + r1;
    row_token[pos1] = t; row_weight[pos1] = w.y;
  }
}

// 16-MFMA cluster: AF indexed [MB+mm], BF[n], acc[MB+mm][n]
#define MFMA_CLUSTER(AF, BF, MB)                                           \
  __builtin_amdgcn_s_setprio(1);                                           \
  _Pragma("unroll") for (int mm = 0; mm < 4; ++mm) {                       \
    _Pragma("unroll") for (int n = 0; n < 4; ++n)                          \
        acc[(MB) + mm][n] = __builtin_amdgcn_mfma_f32_16x16x32_bf16(       \
            AF[(MB) + mm], BF[n], acc[(MB) + mm][n], 0, 0, 0);             \
  }                                                                        \
  __builtin_amdgcn_s_setprio(0);

#define BAR_FENCE()                      \
  __builtin_amdgcn_s_barrier();          \
  asm volatile("" ::: "memory")

// ---------- grouped GEMM 256x256xBK64, 8 waves, 4-phase/K-tile pipeline ----------
// RACE FIX vs R6: per-K-tile vmcnt(6) now sits at END of phase 3, BEFORE the
// closing s_barrier -> the barrier certifies tile kt+1 landed for ALL waves
// before any wave's phase-0 ds_read of it. (vmcnt is per-wave; R6 read right
// after its own vmcnt with no barrier -> cross-wave race -> NaN.)
// FIFO check (steady state, 14 outstanding at p3-end): oldest 8 = all of tile
// kt+1 (6 from kt-1's p2/p3 + 2 from p0) -> vmcnt(6) retires exactly them.
template <int MODE, int KDIM, int NDIM, int NSMAX>
__global__ __launch_bounds__(512, 2) void gemm256_kernel(
    const unsigned short* __restrict__ A, const unsigned short* __restrict__ Bw,
    const float* __restrict__ bias, unsigned short* __restrict__ hOut,
    float* __restrict__ out, const int* __restrict__ row_token,
    const float* __restrict__ row_weight, const int4* __restrict__ sched,
    const int* __restrict__ nsched_p, int nsched_idx) {
  constexpr int NT = KDIM / 64;
  constexpr int NCOL = NDIM / 256;
  constexpr int CHUNK = NSMAX * NCOL / 8;
  const int flat = blockIdx.x;
  const int L = (flat & 7) * CHUNK + (flat >> 3);
  const int sid = L / NCOL;
  const int colblk = L - sid * NCOL;
  if (sid >= nsched_p[nsched_idx]) return;
  int4 s = sched[sid];
  const int row_start = s.x, row_limit = s.y, e = s.z;
  const int colBase = colblk * 256;

  __shared__ __attribute__((aligned(16))) unsigned short As[2][256 * 64];
  __shared__ __attribute__((aligned(16))) unsigned short Bs[2][256 * 64];
  __shared__ __attribute__((aligned(16))) unsigned short Dm[4096];  // dummy 8KB

  const int tid = threadIdx.x;
  const int w = tid >> 6;
  const int lane = tid & 63;
  const int wr = w >> 2;   // 0..1  (M half)
  const int wc = w & 3;    // 0..3  (N quarter)

  // staging: thread covers row i*64 + w*8 + (lane>>3), phys chunk lane&7
  // T2 write side: fetch logical chunk (lane&7)^(row&7), row&7 == lane>>3
  const int srow = w * 8 + (lane >> 3);
  const int schunk = (lane & 7) ^ (lane >> 3);
  const unsigned short* aG[4];
  const unsigned short* bG[4];
  const unsigned short* Bbase = Bw + (size_t)e * ((size_t)NDIM * KDIM);
#pragma unroll
  for (int i = 0; i < 4; ++i) {
    int r = i * 64 + srow;
    int rg = row_start + r;
    rg = rg < row_limit ? rg : (row_limit - 1);
    int arow = (MODE == 0) ? row_token[rg] : rg;
    aG[i] = A + (size_t)arow * KDIM + schunk * 8;
    bG[i] = Bbase + (size_t)(colBase + r) * KDIM + schunk * 8;
  }

  f32x4 zero = {0.f, 0.f, 0.f, 0.f};
  f32x4 acc[8][4];
#pragma unroll
  for (int m = 0; m < 8; ++m)
#pragma unroll
    for (int n = 0; n < 4; ++n) acc[m][n] = zero;

  char* dmy = (char*)Dm + w * 1024;
  // stage one half (2 async16/thread) of matrix for K-tile kt2
  auto stage2 = [&](const unsigned short* const* G, char* mb, int kt2, int half) {
    const int ok = kt2 < NT;
    const size_t koff = ok ? (size_t)kt2 * 128 : 0;
    char* bufb = mb + (size_t)(kt2 & 1) * 32768;
#pragma unroll
    for (int i = half * 2; i < half * 2 + 2; ++i) {
      char* d = ok ? bufb + (i * 8 + w) * 1024 : dmy;
      async16((const char*)G[i] + koff, d);
    }
  };

  const int rl = lane & 15;
  const int ch0 = lane >> 4;
  const int swz = rl & 7;
  const int cOff0 = (ch0 ^ swz) * 16;        // ks0 swizzled chunk byte
  const int cOff1 = ((4 + ch0) ^ swz) * 16;  // ks1
  const int arB = (wr * 128 + rl) * 128;     // A frag row-base byte (+m*2048)
  const int brB = (wc * 64 + rl) * 128;      // B frag row-base byte (+n*2048)

  // prologue: kt0 full (8 loads, oldest group) + kt1 A h0,h1 + B h0 (6)
  stage2(aG, (char*)As, 0, 0); stage2(aG, (char*)As, 0, 1);
  stage2(bG, (char*)Bs, 0, 0); stage2(bG, (char*)Bs, 0, 1);
  asm volatile("" ::: "memory");  // keep kt0 group FIFO-oldest
  stage2(aG, (char*)As, 1, 0); stage2(aG, (char*)As, 1, 1);
  stage2(bG, (char*)Bs, 1, 0);
  asm volatile("s_waitcnt vmcnt(6)" ::: "memory");  // kt0 landed (this wave)
  BAR_FENCE();                                      // kt0 landed (ALL waves)

  for (int kt = 0; kt < NT; ++kt) {
    const char* Ab = (const char*)As + (size_t)(kt & 1) * 32768;
    const char* Bb = (const char*)Bs + (size_t)(kt & 1) * 32768;
    bf16x8 aK0[8], aK1[8], b0[4], b1[4];
    // ---- phase 0: read A-mh0 (both ks) + B-ks0; stage B-h1(kt+1) ----
#pragma unroll
    for (int m = 0; m < 4; ++m) {
      aK0[m] = *(const bf16x8*)(Ab + arB + m * 2048 + cOff0);
      aK1[m] = *(const bf16x8*)(Ab + arB + m * 2048 + cOff1);
    }
#pragma unroll
    for (int n = 0; n < 4; ++n)
      b0[n] = *(const bf16x8*)(Bb + brB + n * 2048 + cOff0);
    stage2(bG, (char*)Bs, kt + 1, 1);
    __builtin_amdgcn_s_barrier();
    asm volatile("s_waitcnt lgkmcnt(0)" ::: "memory");
    __builtin_amdgcn_sched_barrier(0);
    MFMA_CLUSTER(aK0, b0, 0)
    BAR_FENCE();
    // ---- phase 1: read A-mh1 (both ks) ----
#pragma unroll
    for (int m = 4; m < 8; ++m) {
      aK0[m] = *(const bf16x8*)(Ab + arB + m * 2048 + cOff0);
      aK1[m] = *(const bf16x8*)(Ab + arB + m * 2048 + cOff1);
    }
    __builtin_amdgcn_s_barrier();
    asm volatile("s_waitcnt lgkmcnt(0)" ::: "memory");
    __builtin_amdgcn_sched_barrier(0);
    MFMA_CLUSTER(aK0, b0, 4)
    BAR_FENCE();
    // ---- phase 2: read B-ks1; stage A-h0(kt+2) (A region dead after p1) ----
#pragma unroll
    for (int n = 0; n < 4; ++n)
      b1[n] = *(const bf16x8*)(Bb + brB + n * 2048 + cOff1);
    stage2(aG, (char*)As, kt + 2, 0);
    __builtin_amdgcn_s_barrier();
    asm volatile("s_waitcnt lgkmcnt(0)" ::: "memory");
    __builtin_amdgcn_sched_barrier(0);
    MFMA_CLUSTER(aK1, b1, 0)
    BAR_FENCE();
    // ---- phase 3: stage A-h1(kt+2) + B-h0(kt+2) (B region dead after p2) ----
    stage2(aG, (char*)As, kt + 2, 1);
    stage2(bG, (char*)Bs, kt + 2, 0);
    BAR_FENCE();
    MFMA_CLUSTER(aK1, b1, 4)
    // tile kt+1 fully landed for this wave; barrier certifies for ALL waves
    asm volatile("s_waitcnt vmcnt(6)" ::: "memory");
    BAR_FENCE();
  }
  asm volatile("s_waitcnt vmcnt(0)" ::: "memory");  // drain tail dummies

  // epilogue: C/D map col=lane&15, row=(lane>>4)*4+j
  const int cCol = lane & 15;
  const int cRowB = (lane >> 4) * 4;

  if (MODE == 0) {
#pragma unroll
    for (int n = 0; n < 4; ++n) {
      int col = colBase + wc * 64 + n * 16 + cCol;
      float bb = bias[e * NDIM + col];
#pragma unroll
      for (int m = 0; m < 8; ++m) {
#pragma unroll
        for (int j = 0; j < 4; ++j) {
          int r = row_start + wr * 128 + m * 16 + cRowB + j;
          if (r < row_limit) {
            float v = gelu_fast(acc[m][n][j] + bb);
            hOut[(size_t)r * NDIM + col] = f2bf(v);
          }
        }
      }
    }
  } else {
#pragma unroll
    for (int m = 0; m < 8; ++m) {
#pragma unroll
      for (int j = 0; j < 4; ++j) {
        int rr = row_start + wr * 128 + m * 16 + cRowB + j;
        if (rr < row_limit) {
          int tok = row_token[rr];
          float wgt = row_weight[rr];
          float* orow = out + (size_t)tok * NDIM;
#pragma unroll
          for (int n = 0; n < 4; ++n) {
            int col = colBase + wc * 64 + n * 16 + cCol;
            float v = wgt * (acc[m][n][j] + bias[e * NDIM + col]);
            if (MODE == 2) v += orow[col];  // pass A completed (stream order)
            orow[col] = v;
          }
        }
      }
    }
  }
}

// ---------- launch ----------
extern "C" void kernel_launch(void* const* d_in, const int* in_sizes, int n_in,
                              void* d_out, int out_size, void* d_ws, size_t ws_size,
                              hipStream_t stream) {
  const float* x  = (const float*)d_in[0];
  const float* gw = (const float*)d_in[1];
  const float* w1 = (const float*)d_in[2];
  const float* b1 = (const float*)d_in[3];
  const float* w2 = (const float*)d_in[4];
  const float* b2 = (const float*)d_in[5];
  float* out = (float*)d_out;
  float* logits = out + (size_t)T_TOKENS * HID;

  char* ws = (char*)d_ws;
  int* nsched = (int*)ws;
  int* colbase = (int*)(ws + 64);
  int4* sched1  = (int4*)(ws + 512);
  int4* sched2a = (int4*)(ws + 512 + 4352);
  int4* sched2b = (int4*)(ws + 512 + 4352 + 2304);
  int* tok_e01 = (int*)(ws + 16384);
  float2* tok_w = (float2*)(ws + 16384 + 65536);
  int* row_token = (int*)(ws + 16384 + 65536 + 131072);
  float* row_weight = (float*)(ws + 16384 + 65536 + 2 * 131072);
  int* bh  = (int*)(ws + 16384 + 65536 + 3 * 131072);
  int* bhp = bh + 16384;
  const size_t BIG = 1u << 20;
  unsigned short* xb  = (unsigned short*)(ws + BIG);  // 32 MiB
  unsigned short* w1b = xb  + (size_t)16777216;       // 32 MiB
  unsigned short* w2b = w1b + (size_t)16777216;       // 32 MiB
  unsigned short* h   = w2b + (size_t)16777216;       // 128 MiB
  const size_t REQUIRED = BIG + 3ull * 33554432ull + 134217728ull;
  if (ws_size < REQUIRED) return;

  cast_bf16_kernel<<<2048, 256, 0, stream>>>(w1, w1b, 16777216);
  cast_bf16_kernel<<<2048, 256, 0, stream>>>(w2, w2b, 16777216);
  routing_kernel<<<1024, 256, 0, stream>>>(x, gw, logits, xb, bh, tok_e01, tok_w);
  sched_kernel<<<1, 1024, 0, stream>>>(bh, bhp, colbase, sched1, sched2a, sched2b, nsched);
  scatter_kernel<<<1024, 64, 0, stream>>>(tok_e01, tok_w, bhp, colbase,
                                          row_token, row_weight);
  // GEMM1: h = gelu(x @ w1^T + b1); NSMAX=136 -> grid 1088 (%8==0 for T1 remap)
  gemm256_kernel<0, 1024, 2048, 136><<<1088, 512, 0, stream>>>(
      xb, w1b, b1, h, nullptr, row_token, nullptr, sched1, nsched, 0);
  // GEMM2 pass A (slot-0 rows, store) then pass B (slot-1 rows, add); NSMAX=72 -> 288
  gemm256_kernel<1, 2048, 1024, 72><<<288, 512, 0, stream>>>(
      h, w2b, b2, nullptr, out, row_token, row_weight, sched2a, nsched, 1);
  gemm256_kernel<2, 2048, 1024, 72><<<288, 512, 0, stream>>>(
      h, w2b, b2, nullptr, out, row_token, row_weight, sched2b, nsched, 2);
}

// Round 8
// 650.510 us; speedup vs baseline: 2.0912x; 1.0867x over previous
//
#include <hip/hip_runtime.h>
#include <stdint.h>

#define T_TOKENS 16384
#define HID 1024
#define INTERM 2048
#define NEXP 8

typedef __bf16 bf16x8 __attribute__((ext_vector_type(8)));
typedef float f32x4 __attribute__((ext_vector_type(4)));

// ---------- helpers ----------
__device__ __forceinline__ unsigned short f2bf(float f) {
  union { float f; uint32_t u; } v; v.f = f;
  uint32_t u = v.u + 0x7fffu + ((v.u >> 16) & 1u);
  return (unsigned short)(u >> 16);
}

__device__ __forceinline__ void async16(const void* g, void* l) {
  auto gp = (const __attribute__((address_space(1))) uint32_t*)(uintptr_t)g;
  auto lp = (__attribute__((address_space(3))) uint32_t*)(uintptr_t)l;
  __builtin_amdgcn_global_load_lds(gp, lp, 16, 0, 0);
}

// tanh-form gelu via fast exp: max abs err ~3e-4 vs exact erf-gelu
__device__ __forceinline__ float gelu_fast(float v) {
  float s = 1.5957691216f * v + 0.0713548163f * v * v * v;
  return v / (1.f + __expf(-s));
}

// ---------- fp32 -> bf16 cast (weights) ----------
__global__ void cast_bf16_kernel(const float* __restrict__ in,
                                 unsigned short* __restrict__ out, int n) {
  int stride = gridDim.x * blockDim.x;
  for (int i = blockIdx.x * blockDim.x + threadIdx.x; i < (n >> 2); i += stride) {
    float4 v = reinterpret_cast<const float4*>(in)[i];
    ushort4 o;
    o.x = f2bf(v.x); o.y = f2bf(v.y); o.z = f2bf(v.z); o.w = f2bf(v.w);
    reinterpret_cast<ushort4*>(out)[i] = o;
  }
}

// ---------- routing: wave/token dot, LDS histogram (NO global atomics) ----------
__global__ __launch_bounds__(256, 4) void routing_kernel(
    const float* __restrict__ x, const float* __restrict__ gw,
    float* __restrict__ logits, unsigned short* __restrict__ xb,
    int* __restrict__ bh, int* __restrict__ tok_e01, float2* __restrict__ tok_w) {
  __shared__ float4 gws[2048];  // 8 experts x 1024 floats = 32 KB
  __shared__ int lh[16];
  const int tid = threadIdx.x;
  if (tid < 16) lh[tid] = 0;
  for (int i = tid; i < 2048; i += 256)
    gws[i] = reinterpret_cast<const float4*>(gw)[i];
  __syncthreads();

  const int lane = tid & 63;
  const int wave = tid >> 6;
  const int tbase = blockIdx.x * 16 + wave * 4;
#pragma unroll 2
  for (int j = 0; j < 4; ++j) {
    int t = tbase + j;
    const float4* xr = reinterpret_cast<const float4*>(x + (size_t)t * HID);
    float4 xv[4];
#pragma unroll
    for (int q = 0; q < 4; ++q) xv[q] = xr[q * 64 + lane];
    ushort4* xbr = reinterpret_cast<ushort4*>(xb + (size_t)t * HID);
#pragma unroll
    for (int q = 0; q < 4; ++q) {
      ushort4 o;
      o.x = f2bf(xv[q].x); o.y = f2bf(xv[q].y);
      o.z = f2bf(xv[q].z); o.w = f2bf(xv[q].w);
      xbr[q * 64 + lane] = o;
    }
    float acc[NEXP];
#pragma unroll
    for (int e = 0; e < NEXP; ++e) {
      float a = 0.f;
#pragma unroll
      for (int q = 0; q < 4; ++q) {
        float4 g = gws[e * 256 + q * 64 + lane];
        a += xv[q].x * g.x + xv[q].y * g.y + xv[q].z * g.z + xv[q].w * g.w;
      }
      acc[e] = a;
    }
#pragma unroll
    for (int e = 0; e < NEXP; ++e)
#pragma unroll
      for (int off = 32; off > 0; off >>= 1)
        acc[e] += __shfl_xor(acc[e], off, 64);
    if (lane == 0) {
      int i0 = 0; float m0 = acc[0];
#pragma unroll
      for (int e = 1; e < NEXP; ++e) if (acc[e] > m0) { m0 = acc[e]; i0 = e; }
      int i1 = -1; float m1 = -3.4e38f;
#pragma unroll
      for (int e = 0; e < NEXP; ++e) if (e != i0 && acc[e] > m1) { m1 = acc[e]; i1 = e; }
      float w0 = 1.f / (1.f + expf(m1 - m0));
      float w1 = 1.f - w0;
      atomicAdd(&lh[i0], 1);
      atomicAdd(&lh[8 + i1], 1);
      tok_e01[t] = i0 | (i1 << 16);
      tok_w[t] = make_float2(w0, w1);
      float4* lg = reinterpret_cast<float4*>(logits + (size_t)t * NEXP);
      lg[0] = make_float4(acc[0], acc[1], acc[2], acc[3]);
      lg[1] = make_float4(acc[4], acc[5], acc[6], acc[7]);
    }
  }
  __syncthreads();
  if (tid < 16) bh[blockIdx.x * 16 + tid] = lh[tid];
}

// ---------- parallel schedule: column prefix scans + 128-row tile emission ----------
__global__ __launch_bounds__(1024) void sched_kernel(
    const int* __restrict__ bh, int* __restrict__ bhp, int* __restrict__ colbase,
    int4* __restrict__ sched1, int4* __restrict__ sched2a, int4* __restrict__ sched2b,
    int* __restrict__ nsched) {
  const int tid = threadIdx.x;
  const int w = tid >> 6;
  const int lane = tid & 63;
  __shared__ int ct[16];
  __shared__ int offs[8];
  __shared__ int t1o[8], t2ao[8], t2bo[8];

  int carry = 0;
  for (int ch = 0; ch < 16; ++ch) {
    int b = ch * 64 + lane;
    int v = bh[b * 16 + w];
    int incl = v;
#pragma unroll
    for (int d = 1; d < 64; d <<= 1) {
      int tt = __shfl_up(incl, d, 64);
      if (lane >= d) incl += tt;
    }
    bhp[b * 16 + w] = incl - v + carry;
    carry += __shfl(incl, 63, 64);
  }
  if (lane == 0) ct[w] = carry;
  __syncthreads();
  if (tid == 0) {
    int o = 0, s1 = 0, s2a = 0, s2b = 0;
    for (int e = 0; e < NEXP; ++e) {
      offs[e] = o;
      int c1 = ct[e], c2 = ct[8 + e], n = c1 + c2;
      o += n;
      t1o[e] = s1; t2ao[e] = s2a; t2bo[e] = s2b;
      s1 += (n + 127) >> 7; s2a += (c1 + 127) >> 7; s2b += (c2 + 127) >> 7;
    }
    nsched[0] = s1; nsched[1] = s2a; nsched[2] = s2b;
  }
  __syncthreads();
  if (tid < 16) colbase[tid] = offs[tid & 7] + ((tid & 8) ? ct[tid & 7] : 0);
  if (tid < 8) {
    int e = tid;
    int c1 = ct[e], c2 = ct[8 + e], n = c1 + c2, o = offs[e];
    for (int i = 0, t0 = 0; t0 < n; t0 += 128, ++i) {
      int hi = t0 + 128 < n ? t0 + 128 : n;
      sched1[t1o[e] + i] = make_int4(o + t0, o + hi, e, 0);
    }
    for (int i = 0, t0 = 0; t0 < c1; t0 += 128, ++i) {
      int hi = t0 + 128 < c1 ? t0 + 128 : c1;
      sched2a[t2ao[e] + i] = make_int4(o + t0, o + hi, e, 0);
    }
    for (int i = 0, t0 = 0; t0 < c2; t0 += 128, ++i) {
      int hi = t0 + 128 < c2 ? t0 + 128 : c2;
      sched2b[t2bo[e] + i] = make_int4(o + c1 + t0, o + c1 + hi, e, 0);
    }
  }
}

// ---------- scatter: per-block LDS ranks + precomputed bases ----------
__global__ __launch_bounds__(64) void scatter_kernel(
    const int* __restrict__ tok_e01, const float2* __restrict__ tok_w,
    const int* __restrict__ bhp, const int* __restrict__ colbase,
    int* __restrict__ row_token, float* __restrict__ row_weight) {
  __shared__ int lh[16];
  const int tid = threadIdx.x;
  if (tid < 16) lh[tid] = 0;
  __syncthreads();
  if (tid < 16) {
    int t = blockIdx.x * 16 + tid;
    int p = tok_e01[t];
    int e0 = p & 0xffff, e1 = p >> 16;
    float2 w = tok_w[t];
    int r0 = atomicAdd(&lh[e0], 1);
    int pos0 = colbase[e0] + bhp[blockIdx.x * 16 + e0] + r0;
    row_token[pos0] = t; row_weight[pos0] = w.x;
    int r1 = atomicAdd(&lh[8 + e1], 1);
    int pos1 = colbase[8 + e1] + bhp[blockIdx.x * 16 + 8 + e1] + r1;
    row_token[pos1] = t; row_weight[pos1] = w.y;
  }
}

// ---------- grouped GEMM 128x128xBK64, 4 waves, m97-structure ----------
// Single 32KB LDS buffer, plain 2-barrier K-loop, ~4 blocks/CU: inter-block
// wave overlap hides the stage drain (m114 mechanism; m97 = 874 TF proven).
// T2 both-sides swizzle kept (bank conflicts -> 0, verified R5/R7).
// MODE 0: A gathered via row_token, epilogue gelu(.+b1) -> h (bf16)
// MODE 1: A = h rows, out[tok]  = w*(acc+b2)
// MODE 2: A = h rows, out[tok] += w*(acc+b2)
template <int MODE, int KDIM, int NDIM>
__global__ __launch_bounds__(256, 4) void gemm128_kernel(
    const unsigned short* __restrict__ A, const unsigned short* __restrict__ Bw,
    const float* __restrict__ bias, unsigned short* __restrict__ hOut,
    float* __restrict__ out, const int* __restrict__ row_token,
    const float* __restrict__ row_weight, const int4* __restrict__ sched,
    const int* __restrict__ nsched_p, int nsched_idx) {
  const int sid = blockIdx.y;  // blockIdx.x = col (fastest) -> A-tile L2 reuse
  if (sid >= nsched_p[nsched_idx]) return;
  int4 s = sched[sid];
  const int row_start = s.x, row_limit = s.y, e = s.z;
  const int colBase = blockIdx.x * 128;

  __shared__ __attribute__((aligned(16))) unsigned short As[128 * 64];  // 16 KB
  __shared__ __attribute__((aligned(16))) unsigned short Bs[128 * 64];  // 16 KB

  const int tid = threadIdx.x;
  const int wave = tid >> 6;
  const int lane = tid & 63;
  const int wr = wave >> 1;  // 0..1 (M half)
  const int wc = wave & 1;   // 0..1 (N half)

  // staging: thread covers (row = i*32 + tid>>3, phys chunk tid&7); T2 write
  // side fetches logical chunk (tid&7)^(row&7), row&7 == (tid>>3)&7
  const int schunk = (tid & 7) ^ ((tid >> 3) & 7);
  const unsigned short* aG[4];
  const unsigned short* bG[4];
  const unsigned short* Bbase = Bw + (size_t)e * ((size_t)NDIM * KDIM);
#pragma unroll
  for (int i = 0; i < 4; ++i) {
    int r = i * 32 + (tid >> 3);
    int rg = row_start + r;
    rg = rg < row_limit ? rg : (row_limit - 1);  // clamp partial tiles
    int arow = (MODE == 0) ? row_token[rg] : rg;
    aG[i] = A + (size_t)arow * KDIM + schunk * 8;
    bG[i] = Bbase + (size_t)(colBase + r) * KDIM + schunk * 8;
  }

  f32x4 zero = {0.f, 0.f, 0.f, 0.f};
  f32x4 acc[4][4];
#pragma unroll
  for (int m = 0; m < 4; ++m)
#pragma unroll
    for (int n = 0; n < 4; ++n) acc[m][n] = zero;

  const int rl = lane & 15;
  const int ch0 = lane >> 4;
  const int swz = rl & 7;
  const int cOff0 = (ch0 ^ swz) * 16;        // ks0 swizzled chunk byte
  const int cOff1 = ((4 + ch0) ^ swz) * 16;  // ks1
  const int arB = (wr * 64 + rl) * 128;      // A frag row-base byte (+m*2048)
  const int brB = (wc * 64 + rl) * 128;      // B frag row-base byte (+n*2048)

  for (int kt = 0; kt < KDIM / 64; ++kt) {
    if (kt) __syncthreads();  // all waves done reading previous tile
    const size_t koff = (size_t)kt * 64;  // elements (128 B)
#pragma unroll
    for (int i = 0; i < 4; ++i) {
      async16(aG[i] + koff, (char*)As + (i * 4 + wave) * 1024);
      async16(bG[i] + koff, (char*)Bs + (i * 4 + wave) * 1024);
    }
    __syncthreads();  // compiler drains vmcnt(0) before s_barrier: tile ready
#pragma unroll
    for (int ks = 0; ks < 2; ++ks) {
      const int co = ks ? cOff1 : cOff0;
      bf16x8 af[4], bfr[4];
#pragma unroll
      for (int m = 0; m < 4; ++m)
        af[m] = *reinterpret_cast<const bf16x8*>((const char*)As + arB + m * 2048 + co);
#pragma unroll
      for (int n = 0; n < 4; ++n)
        bfr[n] = *reinterpret_cast<const bf16x8*>((const char*)Bs + brB + n * 2048 + co);
#pragma unroll
      for (int m = 0; m < 4; ++m)
#pragma unroll
        for (int n = 0; n < 4; ++n)
          acc[m][n] = __builtin_amdgcn_mfma_f32_16x16x32_bf16(af[m], bfr[n], acc[m][n], 0, 0, 0);
    }
  }

  // epilogue: C/D map col=lane&15, row=(lane>>4)*4+j
  const int cCol = lane & 15;
  const int cRowB = (lane >> 4) * 4;

  if (MODE == 0) {
#pragma unroll
    for (int n = 0; n < 4; ++n) {
      int col = colBase + wc * 64 + n * 16 + cCol;
      float bb = bias[e * NDIM + col];
#pragma unroll
      for (int m = 0; m < 4; ++m) {
#pragma unroll
        for (int j = 0; j < 4; ++j) {
          int r = row_start + wr * 64 + m * 16 + cRowB + j;
          if (r < row_limit) {
            float v = gelu_fast(acc[m][n][j] + bb);
            hOut[(size_t)r * NDIM + col] = f2bf(v);
          }
        }
      }
    }
  } else {
#pragma unroll
    for (int m = 0; m < 4; ++m) {
#pragma unroll
      for (int j = 0; j < 4; ++j) {
        int rr = row_start + wr * 64 + m * 16 + cRowB + j;
        if (rr < row_limit) {
          int tok = row_token[rr];
          float wgt = row_weight[rr];
          float* orow = out + (size_t)tok * NDIM;
#pragma unroll
          for (int n = 0; n < 4; ++n) {
            int col = colBase + wc * 64 + n * 16 + cCol;
            float v = wgt * (acc[m][n][j] + bias[e * NDIM + col]);
            if (MODE == 2) v += orow[col];  // pass A completed (stream order)
            orow[col] = v;
          }
        }
      }
    }
  }
}

// ---------- launch ----------
extern "C" void kernel_launch(void* const* d_in, const int* in_sizes, int n_in,
                              void* d_out, int out_size, void* d_ws, size_t ws_size,
                              hipStream_t stream) {
  const float* x  = (const float*)d_in[0];
  const float* gw = (const float*)d_in[1];
  const float* w1 = (const float*)d_in[2];
  const float* b1 = (const float*)d_in[3];
  const float* w2 = (const float*)d_in[4];
  const float* b2 = (const float*)d_in[5];
  float* out = (float*)d_out;
  float* logits = out + (size_t)T_TOKENS * HID;

  char* ws = (char*)d_ws;
  int* nsched = (int*)ws;
  int* colbase = (int*)(ws + 64);
  int4* sched1  = (int4*)(ws + 512);
  int4* sched2a = (int4*)(ws + 512 + 4352);
  int4* sched2b = (int4*)(ws + 512 + 4352 + 2304);
  int* tok_e01 = (int*)(ws + 16384);
  float2* tok_w = (float2*)(ws + 16384 + 65536);
  int* row_token = (int*)(ws + 16384 + 65536 + 131072);
  float* row_weight = (float*)(ws + 16384 + 65536 + 2 * 131072);
  int* bh  = (int*)(ws + 16384 + 65536 + 3 * 131072);
  int* bhp = bh + 16384;
  const size_t BIG = 1u << 20;
  unsigned short* xb  = (unsigned short*)(ws + BIG);  // 32 MiB
  unsigned short* w1b = xb  + (size_t)16777216;       // 32 MiB
  unsigned short* w2b = w1b + (size_t)16777216;       // 32 MiB
  unsigned short* h   = w2b + (size_t)16777216;       // 128 MiB
  const size_t REQUIRED = BIG + 3ull * 33554432ull + 134217728ull;
  if (ws_size < REQUIRED) return;

  cast_bf16_kernel<<<2048, 256, 0, stream>>>(w1, w1b, 16777216);
  cast_bf16_kernel<<<2048, 256, 0, stream>>>(w2, w2b, 16777216);
  routing_kernel<<<1024, 256, 0, stream>>>(x, gw, logits, xb, bh, tok_e01, tok_w);
  sched_kernel<<<1, 1024, 0, stream>>>(bh, bhp, colbase, sched1, sched2a, sched2b, nsched);
  scatter_kernel<<<1024, 64, 0, stream>>>(tok_e01, tok_w, bhp, colbase,
                                          row_token, row_weight);
  // GEMM1: h = gelu(x @ w1^T + b1); <=263 row-tiles x 16 col-blocks
  gemm128_kernel<0, 1024, 2048><<<dim3(16, 264), 256, 0, stream>>>(
      xb, w1b, b1, h, nullptr, row_token, nullptr, sched1, nsched, 0);
  // GEMM2 pass A (slot-0 rows, store) then pass B (slot-1 rows, add)
  gemm128_kernel<1, 2048, 1024><<<dim3(8, 136), 256, 0, stream>>>(
      h, w2b, b2, nullptr, out, row_token, row_weight, sched2a, nsched, 1);
  gemm128_kernel<2, 2048, 1024><<<dim3(8, 136), 256, 0, stream>>>(
      h, w2b, b2, nullptr, out, row_token, row_weight, sched2b, nsched, 2);
}

// Round 9
// 590.344 us; speedup vs baseline: 2.3043x; 1.1019x over previous
//
#include <hip/hip_runtime.h>
#include <stdint.h>

#define T_TOKENS 16384
#define HID 1024
#define INTERM 2048
#define NEXP 8

typedef __bf16 bf16x8 __attribute__((ext_vector_type(8)));
typedef float f32x4 __attribute__((ext_vector_type(4)));

// ---------- helpers ----------
__device__ __forceinline__ unsigned short f2bf(float f) {
  union { float f; uint32_t u; } v; v.f = f;
  uint32_t u = v.u + 0x7fffu + ((v.u >> 16) & 1u);
  return (unsigned short)(u >> 16);
}

__device__ __forceinline__ float bf2f(unsigned short u) {
  union { uint32_t u; float f; } v; v.u = ((uint32_t)u) << 16;
  return v.f;
}

__device__ __forceinline__ void async16(const void* g, void* l) {
  auto gp = (const __attribute__((address_space(1))) uint32_t*)(uintptr_t)g;
  auto lp = (__attribute__((address_space(3))) uint32_t*)(uintptr_t)l;
  __builtin_amdgcn_global_load_lds(gp, lp, 16, 0, 0);
}

// tanh-form gelu via fast exp: max abs err ~3e-4 vs exact erf-gelu
__device__ __forceinline__ float gelu_fast(float v) {
  float s = 1.5957691216f * v + 0.0713548163f * v * v * v;
  return v / (1.f + __expf(-s));
}

// ---------- fp32 -> bf16 cast (weights) ----------
__global__ void cast_bf16_kernel(const float* __restrict__ in,
                                 unsigned short* __restrict__ out, int n) {
  int stride = gridDim.x * blockDim.x;
  for (int i = blockIdx.x * blockDim.x + threadIdx.x; i < (n >> 2); i += stride) {
    float4 v = reinterpret_cast<const float4*>(in)[i];
    ushort4 o;
    o.x = f2bf(v.x); o.y = f2bf(v.y); o.z = f2bf(v.z); o.w = f2bf(v.w);
    reinterpret_cast<ushort4*>(out)[i] = o;
  }
}

// ---------- routing: wave/token dot, LDS histogram (NO global atomics) ----------
__global__ __launch_bounds__(256, 4) void routing_kernel(
    const float* __restrict__ x, const float* __restrict__ gw,
    float* __restrict__ logits, unsigned short* __restrict__ xb,
    int* __restrict__ bh, int* __restrict__ tok_e01, float2* __restrict__ tok_w) {
  __shared__ float4 gws[2048];  // 8 experts x 1024 floats = 32 KB
  __shared__ int lh[16];
  const int tid = threadIdx.x;
  if (tid < 16) lh[tid] = 0;
  for (int i = tid; i < 2048; i += 256)
    gws[i] = reinterpret_cast<const float4*>(gw)[i];
  __syncthreads();

  const int lane = tid & 63;
  const int wave = tid >> 6;
  const int tbase = blockIdx.x * 16 + wave * 4;
#pragma unroll 2
  for (int j = 0; j < 4; ++j) {
    int t = tbase + j;
    const float4* xr = reinterpret_cast<const float4*>(x + (size_t)t * HID);
    float4 xv[4];
#pragma unroll
    for (int q = 0; q < 4; ++q) xv[q] = xr[q * 64 + lane];
    ushort4* xbr = reinterpret_cast<ushort4*>(xb + (size_t)t * HID);
#pragma unroll
    for (int q = 0; q < 4; ++q) {
      ushort4 o;
      o.x = f2bf(xv[q].x); o.y = f2bf(xv[q].y);
      o.z = f2bf(xv[q].z); o.w = f2bf(xv[q].w);
      xbr[q * 64 + lane] = o;
    }
    float acc[NEXP];
#pragma unroll
    for (int e = 0; e < NEXP; ++e) {
      float a = 0.f;
#pragma unroll
      for (int q = 0; q < 4; ++q) {
        float4 g = gws[e * 256 + q * 64 + lane];
        a += xv[q].x * g.x + xv[q].y * g.y + xv[q].z * g.z + xv[q].w * g.w;
      }
      acc[e] = a;
    }
#pragma unroll
    for (int e = 0; e < NEXP; ++e)
#pragma unroll
      for (int off = 32; off > 0; off >>= 1)
        acc[e] += __shfl_xor(acc[e], off, 64);
    if (lane == 0) {
      int i0 = 0; float m0 = acc[0];
#pragma unroll
      for (int e = 1; e < NEXP; ++e) if (acc[e] > m0) { m0 = acc[e]; i0 = e; }
      int i1 = -1; float m1 = -3.4e38f;
#pragma unroll
      for (int e = 0; e < NEXP; ++e) if (e != i0 && acc[e] > m1) { m1 = acc[e]; i1 = e; }
      float w0 = 1.f / (1.f + expf(m1 - m0));
      float w1 = 1.f - w0;
      atomicAdd(&lh[i0], 1);
      atomicAdd(&lh[8 + i1], 1);
      tok_e01[t] = i0 | (i1 << 16);
      tok_w[t] = make_float2(w0, w1);
      float4* lg = reinterpret_cast<float4*>(logits + (size_t)t * NEXP);
      lg[0] = make_float4(acc[0], acc[1], acc[2], acc[3]);
      lg[1] = make_float4(acc[4], acc[5], acc[6], acc[7]);
    }
  }
  __syncthreads();
  if (tid < 16) bh[blockIdx.x * 16 + tid] = lh[tid];
}

// ---------- parallel schedule: column prefix scans + 128-row tile emission ----------
// Single tile list (expert-grouped rows) used by BOTH GEMMs.
__global__ __launch_bounds__(1024) void sched_kernel(
    const int* __restrict__ bh, int* __restrict__ bhp, int* __restrict__ colbase,
    int4* __restrict__ sched1, int* __restrict__ nsched) {
  const int tid = threadIdx.x;
  const int w = tid >> 6;
  const int lane = tid & 63;
  __shared__ int ct[16];
  __shared__ int offs[8];
  __shared__ int t1o[8];

  int carry = 0;
  for (int ch = 0; ch < 16; ++ch) {
    int b = ch * 64 + lane;
    int v = bh[b * 16 + w];
    int incl = v;
#pragma unroll
    for (int d = 1; d < 64; d <<= 1) {
      int tt = __shfl_up(incl, d, 64);
      if (lane >= d) incl += tt;
    }
    bhp[b * 16 + w] = incl - v + carry;
    carry += __shfl(incl, 63, 64);
  }
  if (lane == 0) ct[w] = carry;
  __syncthreads();
  if (tid == 0) {
    int o = 0, s1 = 0;
    for (int e = 0; e < NEXP; ++e) {
      offs[e] = o;
      int n = ct[e] + ct[8 + e];
      o += n;
      t1o[e] = s1;
      s1 += (n + 127) >> 7;
    }
    nsched[0] = s1;
  }
  __syncthreads();
  if (tid < 16) colbase[tid] = offs[tid & 7] + ((tid & 8) ? ct[tid & 7] : 0);
  if (tid < 8) {
    int e = tid;
    int n = ct[e] + ct[8 + e], o = offs[e];
    for (int i = 0, t0 = 0; t0 < n; t0 += 128, ++i) {
      int hi = t0 + 128 < n ? t0 + 128 : n;
      sched1[t1o[e] + i] = make_int4(o + t0, o + hi, e, 0);
    }
  }
}

// ---------- scatter: per-block LDS ranks + precomputed bases ----------
__global__ __launch_bounds__(64) void scatter_kernel(
    const int* __restrict__ tok_e01, const float2* __restrict__ tok_w,
    const int* __restrict__ bhp, const int* __restrict__ colbase,
    int* __restrict__ row_token, float* __restrict__ row_weight,
    int2* __restrict__ tok_pos) {
  __shared__ int lh[16];
  const int tid = threadIdx.x;
  if (tid < 16) lh[tid] = 0;
  __syncthreads();
  if (tid < 16) {
    int t = blockIdx.x * 16 + tid;
    int p = tok_e01[t];
    int e0 = p & 0xffff, e1 = p >> 16;
    float2 w = tok_w[t];
    int r0 = atomicAdd(&lh[e0], 1);
    int pos0 = colbase[e0] + bhp[blockIdx.x * 16 + e0] + r0;
    row_token[pos0] = t; row_weight[pos0] = w.x;
    int r1 = atomicAdd(&lh[8 + e1], 1);
    int pos1 = colbase[8 + e1] + bhp[blockIdx.x * 16 + 8 + e1] + r1;
    row_token[pos1] = t; row_weight[pos1] = w.y;
    tok_pos[t] = make_int2(pos0, pos1);
  }
}

// ---------- grouped GEMM 128x128xBK64, 4 waves, m97-structure ----------
// Single 32KB LDS buffer, plain 2-barrier K-loop, ~4 blocks/CU (m97 = 874 TF
// proven); T2 both-sides swizzle (bank conflicts 0, verified R5/R7/R8).
// MODE 0: A gathered via row_token, epilogue gelu(.+b1) -> h (bf16)
// MODE 1: A = h rows (contiguous), epilogue y[row] = bf16(w*(acc+b2))
template <int MODE, int KDIM, int NDIM>
__global__ __launch_bounds__(256, 4) void gemm128_kernel(
    const unsigned short* __restrict__ A, const unsigned short* __restrict__ Bw,
    const float* __restrict__ bias, unsigned short* __restrict__ hOut,
    const int* __restrict__ row_token, const float* __restrict__ row_weight,
    const int4* __restrict__ sched, const int* __restrict__ nsched_p) {
  const int sid = blockIdx.y;  // blockIdx.x = col (fastest) -> XCD = col%8
  if (sid >= nsched_p[0]) return;
  int4 s = sched[sid];
  const int row_start = s.x, row_limit = s.y, e = s.z;
  const int colBase = blockIdx.x * 128;

  __shared__ __attribute__((aligned(16))) unsigned short As[128 * 64];  // 16 KB
  __shared__ __attribute__((aligned(16))) unsigned short Bs[128 * 64];  // 16 KB

  const int tid = threadIdx.x;
  const int wave = tid >> 6;
  const int lane = tid & 63;
  const int wr = wave >> 1;  // 0..1 (M half)
  const int wc = wave & 1;   // 0..1 (N half)

  // staging: thread covers (row = i*32 + tid>>3, phys chunk tid&7); T2 write
  // side fetches logical chunk (tid&7)^(row&7), row&7 == (tid>>3)&7
  const int schunk = (tid & 7) ^ ((tid >> 3) & 7);
  const unsigned short* aG[4];
  const unsigned short* bG[4];
  const unsigned short* Bbase = Bw + (size_t)e * ((size_t)NDIM * KDIM);
#pragma unroll
  for (int i = 0; i < 4; ++i) {
    int r = i * 32 + (tid >> 3);
    int rg = row_start + r;
    rg = rg < row_limit ? rg : (row_limit - 1);  // clamp partial tiles
    int arow = (MODE == 0) ? row_token[rg] : rg;
    aG[i] = A + (size_t)arow * KDIM + schunk * 8;
    bG[i] = Bbase + (size_t)(colBase + r) * KDIM + schunk * 8;
  }

  f32x4 zero = {0.f, 0.f, 0.f, 0.f};
  f32x4 acc[4][4];
#pragma unroll
  for (int m = 0; m < 4; ++m)
#pragma unroll
    for (int n = 0; n < 4; ++n) acc[m][n] = zero;

  const int rl = lane & 15;
  const int ch0 = lane >> 4;
  const int swz = rl & 7;
  const int cOff0 = (ch0 ^ swz) * 16;        // ks0 swizzled chunk byte
  const int cOff1 = ((4 + ch0) ^ swz) * 16;  // ks1
  const int arB = (wr * 64 + rl) * 128;      // A frag row-base byte (+m*2048)
  const int brB = (wc * 64 + rl) * 128;      // B frag row-base byte (+n*2048)

  for (int kt = 0; kt < KDIM / 64; ++kt) {
    if (kt) __syncthreads();  // all waves done reading previous tile
    const size_t koff = (size_t)kt * 64;  // elements (128 B)
#pragma unroll
    for (int i = 0; i < 4; ++i) {
      async16(aG[i] + koff, (char*)As + (i * 4 + wave) * 1024);
      async16(bG[i] + koff, (char*)Bs + (i * 4 + wave) * 1024);
    }
    __syncthreads();  // compiler drains vmcnt(0) before s_barrier: tile ready
#pragma unroll
    for (int ks = 0; ks < 2; ++ks) {
      const int co = ks ? cOff1 : cOff0;
      bf16x8 af[4], bfr[4];
#pragma unroll
      for (int m = 0; m < 4; ++m)
        af[m] = *reinterpret_cast<const bf16x8*>((const char*)As + arB + m * 2048 + co);
#pragma unroll
      for (int n = 0; n < 4; ++n)
        bfr[n] = *reinterpret_cast<const bf16x8*>((const char*)Bs + brB + n * 2048 + co);
#pragma unroll
      for (int m = 0; m < 4; ++m)
#pragma unroll
        for (int n = 0; n < 4; ++n)
          acc[m][n] = __builtin_amdgcn_mfma_f32_16x16x32_bf16(af[m], bfr[n], acc[m][n], 0, 0, 0);
    }
  }

  // epilogue: C/D map col=lane&15, row=(lane>>4)*4+j
  const int cCol = lane & 15;
  const int cRowB = (lane >> 4) * 4;

  if (MODE == 0) {
#pragma unroll
    for (int n = 0; n < 4; ++n) {
      int col = colBase + wc * 64 + n * 16 + cCol;
      float bb = bias[e * NDIM + col];
#pragma unroll
      for (int m = 0; m < 4; ++m) {
#pragma unroll
        for (int j = 0; j < 4; ++j) {
          int r = row_start + wr * 64 + m * 16 + cRowB + j;
          if (r < row_limit) {
            float v = gelu_fast(acc[m][n][j] + bb);
            hOut[(size_t)r * NDIM + col] = f2bf(v);
          }
        }
      }
    }
  } else {
#pragma unroll
    for (int m = 0; m < 4; ++m) {
#pragma unroll
      for (int j = 0; j < 4; ++j) {
        int rr = row_start + wr * 64 + m * 16 + cRowB + j;
        if (rr < row_limit) {
          float wgt = row_weight[rr];
          unsigned short* yrow = hOut + (size_t)rr * NDIM;
#pragma unroll
          for (int n = 0; n < 4; ++n) {
            int col = colBase + wc * 64 + n * 16 + cCol;
            yrow[col] = f2bf(wgt * (acc[m][n][j] + bias[e * NDIM + col]));
          }
        }
      }
    }
  }
}

// ---------- combine: out[t] = y[pos0] + y[pos1] (wave per token) ----------
__global__ __launch_bounds__(256) void combine_kernel(
    const unsigned short* __restrict__ y, const int2* __restrict__ tok_pos,
    float* __restrict__ out) {
  const int t = blockIdx.x * 4 + (threadIdx.x >> 6);
  const int lane = threadIdx.x & 63;
  int2 p = tok_pos[t];
  const ushort4* y0 = reinterpret_cast<const ushort4*>(y + (size_t)p.x * HID);
  const ushort4* y1 = reinterpret_cast<const ushort4*>(y + (size_t)p.y * HID);
  float4* o = reinterpret_cast<float4*>(out + (size_t)t * HID);
#pragma unroll
  for (int q = 0; q < 4; ++q) {
    ushort4 a = y0[q * 64 + lane];
    ushort4 b = y1[q * 64 + lane];
    float4 r;
    r.x = bf2f(a.x) + bf2f(b.x);
    r.y = bf2f(a.y) + bf2f(b.y);
    r.z = bf2f(a.z) + bf2f(b.z);
    r.w = bf2f(a.w) + bf2f(b.w);
    o[q * 64 + lane] = r;
  }
}

// ---------- launch ----------
extern "C" void kernel_launch(void* const* d_in, const int* in_sizes, int n_in,
                              void* d_out, int out_size, void* d_ws, size_t ws_size,
                              hipStream_t stream) {
  const float* x  = (const float*)d_in[0];
  const float* gw = (const float*)d_in[1];
  const float* w1 = (const float*)d_in[2];
  const float* b1 = (const float*)d_in[3];
  const float* w2 = (const float*)d_in[4];
  const float* b2 = (const float*)d_in[5];
  float* out = (float*)d_out;
  float* logits = out + (size_t)T_TOKENS * HID;

  char* ws = (char*)d_ws;
  int* nsched = (int*)ws;
  int* colbase = (int*)(ws + 64);
  int4* sched1  = (int4*)(ws + 512);               // <=264 entries
  int* tok_e01 = (int*)(ws + 16384);                              // 64 KB
  float2* tok_w = (float2*)(ws + 16384 + 65536);                  // 128 KB
  int* row_token = (int*)(ws + 16384 + 65536 + 131072);           // 128 KB
  float* row_weight = (float*)(ws + 16384 + 65536 + 2 * 131072);  // 128 KB
  int* bh  = (int*)(ws + 16384 + 65536 + 3 * 131072);             // 64 KB
  int* bhp = bh + 16384;                                          // 64 KB
  int2* tok_pos = (int2*)(ws + 16384 + 65536 + 3 * 131072 + 2 * 65536);  // 128 KB
  const size_t BIG = 1u << 20;
  unsigned short* xb  = (unsigned short*)(ws + BIG);  // 32 MiB
  unsigned short* w1b = xb  + (size_t)16777216;       // 32 MiB
  unsigned short* w2b = w1b + (size_t)16777216;       // 32 MiB
  unsigned short* h   = w2b + (size_t)16777216;       // 128 MiB
  // y (32768 x 1024 bf16 = 64 MiB) aliases [xb, w1b]: both dead after GEMM1
  unsigned short* y = xb;
  const size_t REQUIRED = BIG + 3ull * 33554432ull + 134217728ull;
  if (ws_size < REQUIRED) return;

  cast_bf16_kernel<<<2048, 256, 0, stream>>>(w1, w1b, 16777216);
  cast_bf16_kernel<<<2048, 256, 0, stream>>>(w2, w2b, 16777216);
  routing_kernel<<<1024, 256, 0, stream>>>(x, gw, logits, xb, bh, tok_e01, tok_w);
  sched_kernel<<<1, 1024, 0, stream>>>(bh, bhp, colbase, sched1, nsched);
  scatter_kernel<<<1024, 64, 0, stream>>>(tok_e01, tok_w, bhp, colbase,
                                          row_token, row_weight, tok_pos);
  // GEMM1: h = gelu(x @ w1^T + b1); <=263 row-tiles x 16 col-blocks
  gemm128_kernel<0, 1024, 2048><<<dim3(16, 264), 256, 0, stream>>>(
      xb, w1b, b1, h, row_token, nullptr, sched1, nsched);
  // GEMM2 single pass: y[row] = bf16(w*(h @ w2^T + b2)) for all 2T rows
  gemm128_kernel<1, 2048, 1024><<<dim3(8, 264), 256, 0, stream>>>(
      h, w2b, b2, y, row_token, row_weight, sched1, nsched);
  // combine: out[t] = y[pos0(t)] + y[pos1(t)]
  combine_kernel<<<4096, 256, 0, stream>>>(y, tok_pos, out);
}